// Round 1
// 1171.375 us; speedup vs baseline: 1.2519x; 1.2519x over previous
//
#include <hip/hip_runtime.h>
#include <stdint.h>

#define E_ENT 50000
#define R_REL 500
#define NEDGE 500000
#define DD 256
#define D2 512
#define KSPLIT 50
#define KCHUNK 1000

typedef unsigned short u16;
typedef unsigned int u32;
typedef __attribute__((ext_vector_type(8))) short bf16x8;
typedef __attribute__((ext_vector_type(4))) float f32x4;

__device__ __forceinline__ float bf2f(u16 u) {
  union { u32 i; float f; } v; v.i = ((u32)u) << 16; return v.f;
}
__device__ __forceinline__ u16 f2bf(float f) {
  union { float f; u32 i; } v; v.f = f;
  u32 r = v.i + 0x7fffu + ((v.i >> 16) & 1u);
  return (u16)(r >> 16);
}
__device__ __forceinline__ float lrelu(float x) { return x > 0.f ? x : 0.01f * x; }

__device__ __forceinline__ uint4 ld4g(const u16* p, bool v) {
  if (v) return *(const uint4*)p;
  return make_uint4(0u, 0u, 0u, 0u);
}

// Swizzled LDS layout: element (col, e) of a [col][64e] bf16 tile at u16 offset
//   col*64 + (((e>>3) ^ col ^ (col>>3)) & 7)*8 + (e&7)
// Bank math: writes (col=nq*8+2i, e per-lane) spread 32 banks 2-way (was 16-way
// at stride 72); b128 reads (col=base+l15, e-octet=ks*4+lq) stay 8-lanes per
// 4-bank group (balanced). col^(col>>3) keeps bit0..2 diversity on BOTH sides.
__device__ __forceinline__ int lds_addr(int col, int e) {
  return col * 64 + ((((e >> 3) ^ col ^ (col >> 3)) & 7) << 3) + (e & 7);
}

// transpose-pack: two e-rows (x = e, y = e+1), 8 cols each -> 8 ds_write_b32
__device__ __forceinline__ void pack_store(u16* __restrict__ lds, int colBase, int e,
                                           const uint4& x, const uint4& y) {
  const u32* xp = (const u32*)&x;
  const u32* yp = (const u32*)&y;
#pragma unroll
  for (int i = 0; i < 4; ++i) {
    u32 xv = xp[i], yv = yp[i];
    u32 lo = (xv & 0xffffu) | (yv << 16);
    u32 hi = (xv >> 16) | (yv & 0xffff0000u);
    int c0 = colBase + 2 * i;
    *(u32*)(lds + lds_addr(c0, e)) = lo;
    *(u32*)(lds + lds_addr(c0 + 1, e)) = hi;
  }
}

// ---------------- f32 -> bf16 cast (4 elems/thread) ----------------
__global__ void k_cast(const float* __restrict__ in, u16* __restrict__ out, int n4) {
  int i = blockIdx.x * 256 + threadIdx.x;
  if (i < n4) {
    float4 v = *(const float4*)(in + (size_t)i * 4);
    uint2 o;
    o.x = (u32)f2bf(v.x) | ((u32)f2bf(v.y) << 16);
    o.y = (u32)f2bf(v.z) | ((u32)f2bf(v.w) << 16);
    *(uint2*)(out + (size_t)i * 4) = o;
  }
}

// ---------------- W [E,500] f32 -> WB [E,512] bf16 (pad 0) + fp32 col sums ----------------
__global__ __launch_bounds__(256) void k_castW(const float* __restrict__ W,
                                               u16* __restrict__ WB,
                                               float* __restrict__ sums) {
  int tid = threadIdx.x;
  int c0 = tid * 2;
  int r0 = blockIdx.x * 64;
  bool valid = c0 < R_REL;
  float s0 = 0.f, s1 = 0.f;
  for (int e = 0; e < 64; ++e) {
    int row = r0 + e;
    if (row >= E_ENT) break;
    u32 out = 0;
    if (valid) {
      float2 v = *(const float2*)(W + (size_t)row * R_REL + c0);
      s0 += v.x; s1 += v.y;
      out = (u32)f2bf(v.x) | ((u32)f2bf(v.y) << 16);
    }
    *(u32*)(WB + (size_t)row * D2 + c0) = out;
  }
  if (valid) {
    atomicAdd(&sums[c0], s0);
    atomicAdd(&sums[c0 + 1], s1);
  }
}

// ---------------- CSR build ----------------
__global__ void k_hist(const int* __restrict__ rows, int* __restrict__ cnt) {
  int i = blockIdx.x * 256 + threadIdx.x;
  if (i < NEDGE) atomicAdd(&cnt[rows[i]], 1);
}

__global__ void k_bsum(const int* __restrict__ cnt, int* __restrict__ bsum) {
  __shared__ int sb[256];
  int t = threadIdx.x, i = blockIdx.x * 256 + t;
  sb[t] = (i < E_ENT) ? cnt[i] : 0;
  __syncthreads();
  for (int s = 128; s; s >>= 1) { if (t < s) sb[t] += sb[t + s]; __syncthreads(); }
  if (t == 0) bsum[blockIdx.x] = sb[0];
}

__global__ void k_scanb(const int* __restrict__ bsum, int* __restrict__ boff, int nb) {
  __shared__ int sb[256];
  int t = threadIdx.x;
  int v = (t < nb) ? bsum[t] : 0;
  sb[t] = v;
  __syncthreads();
  for (int o = 1; o < 256; o <<= 1) {
    int x = (t >= o) ? sb[t - o] : 0;
    __syncthreads();
    sb[t] += x;
    __syncthreads();
  }
  if (t < nb) boff[t] = sb[t] - v;
}

__global__ void k_apply(const int* __restrict__ cnt, const int* __restrict__ boff,
                        int* __restrict__ ptr, int* __restrict__ cur) {
  __shared__ int sb[256];
  int t = threadIdx.x, b = blockIdx.x, i = b * 256 + t;
  int v = (i < E_ENT) ? cnt[i] : 0;
  sb[t] = v;
  __syncthreads();
  for (int o = 1; o < 256; o <<= 1) {
    int x = (t >= o) ? sb[t - o] : 0;
    __syncthreads();
    sb[t] += x;
    __syncthreads();
  }
  if (i < E_ENT) { int ex = boff[b] + sb[t] - v; ptr[i] = ex; cur[i] = ex; }
  if (b == 0 && t == 0) ptr[E_ENT] = NEDGE;
}

__global__ void k_scat_e(const int* __restrict__ rows, const int* __restrict__ cols,
                         const int* __restrict__ rels, int* __restrict__ cur,
                         int* __restrict__ cs, int* __restrict__ rs) {
  int i = blockIdx.x * 256 + threadIdx.x;
  if (i < NEDGE) {
    int p = atomicAdd(&cur[rows[i]], 1);
    cs[p] = cols[i];
    rs[p] = rels[i];
  }
}

__global__ void k_scat_m(const int* __restrict__ rows, const int* __restrict__ cols,
                         const float* __restrict__ vals, int* __restrict__ cur,
                         int* __restrict__ cs, float* __restrict__ vs) {
  int i = blockIdx.x * 256 + threadIdx.x;
  if (i < NEDGE) {
    int p = atomicAdd(&cur[rows[i]], 1);
    cs[p] = cols[i];
    vs[p] = vals[i];
  }
}

// ---------------- fused [HB|TB]^T @ X (M=2x500,K=50000,N=256), split-K, MFMA ------------
// HB/TB: bf16 [E,512]; XB: bf16 [E,256]. grid (32 = 16mt x 2nt, KSPLIT).
// threads <128 stage the HB A-tile, threads >=128 the TB A-tile; one B-staging
// feeds MFMAs for both -> per-dispatch MFMA doubles at same staging cost, XB read once.
__device__ __forceinline__ void wtx_load(const u16* __restrict__ WSel, const u16* __restrict__ XB,
                                         int eb, int e_end, int r0, int n0,
                                         int ap, int aq, int ep0, int ep1, int nq,
                                         uint4& a0, uint4& a1, uint4& b00, uint4& b01,
                                         uint4& b10, uint4& b11) {
  int ee = e_end - eb;
  const u16* p = WSel + (size_t)(eb + 2 * ap) * D2 + r0 + aq * 8;
  a0 = ld4g(p, 2 * ap < ee);
  a1 = ld4g(p + D2, 2 * ap + 1 < ee);
  const u16* q0 = XB + (size_t)(eb + 2 * ep0) * DD + n0 + nq * 8;
  b00 = ld4g(q0, 2 * ep0 < ee);
  b01 = ld4g(q0 + DD, 2 * ep0 + 1 < ee);
  const u16* q1 = XB + (size_t)(eb + 2 * ep1) * DD + n0 + nq * 8;
  b10 = ld4g(q1, 2 * ep1 < ee);
  b11 = ld4g(q1 + DD, 2 * ep1 + 1 < ee);
}

__global__ __launch_bounds__(256) void k_wtx(const u16* __restrict__ HB,
                                             const u16* __restrict__ TB,
                                             const u16* __restrict__ XB,
                                             float* __restrict__ P) {
  __shared__ __align__(16) u16 lsa2[2 * 32 * 64];  // [H|T] A-tiles, swizzled
  __shared__ __align__(16) u16 lsb[128 * 64];      // B-tile, swizzled
  const int tid = threadIdx.x;
  const int mt = blockIdx.x >> 1, nt = blockIdx.x & 1;
  const int r0 = mt * 32, n0 = nt * 128;
  const int lane = tid & 63, wv = tid >> 6;
  const int wm = (wv & 1) * 16, wn = (wv >> 1) * 64;
  const int l15 = lane & 15, lq = lane >> 4;
  const int ap = (tid & 127) >> 2, aq = tid & 3;  // A tile: e-pair, r-oct (per half)
  const int ep0 = tid >> 4, nq = tid & 15;        // B tiles: e-pairs ep0, ep0+16
  const int ep1 = ep0 + 16;
  const u16* WSel = (tid < 128) ? HB : TB;
  u16* lsaSel = lsa2 + (tid >> 7) * (32 * 64);
  const int e_begin = blockIdx.y * KCHUNK;
  const int e_end = min(e_begin + KCHUNK, E_ENT);
  const int iters = (e_end - e_begin + 63) >> 6;

  f32x4 accH[4], accT[4];
#pragma unroll
  for (int t = 0; t < 4; ++t) { accH[t] = (f32x4)0.f; accT[t] = (f32x4)0.f; }

  uint4 a0, a1, b00, b01, b10, b11;
  wtx_load(WSel, XB, e_begin, e_end, r0, n0, ap, aq, ep0, ep1, nq, a0, a1, b00, b01, b10, b11);

  int eb = e_begin;
  for (int it = 0; it < iters; ++it) {
    __syncthreads();
    pack_store(lsaSel, aq * 8, 2 * ap, a0, a1);
    pack_store(lsb, nq * 8, 2 * ep0, b00, b01);
    pack_store(lsb, nq * 8, 2 * ep1, b10, b11);
    __syncthreads();
    eb += 64;
    if (it + 1 < iters)
      wtx_load(WSel, XB, eb, e_end, r0, n0, ap, aq, ep0, ep1, nq, a0, a1, b00, b01, b10, b11);
#pragma unroll
    for (int ks = 0; ks < 2; ++ks) {
      bf16x8 afH = *(const bf16x8*)(lsa2 + lds_addr(wm + l15, ks * 32 + lq * 8));
      bf16x8 afT = *(const bf16x8*)(lsa2 + 32 * 64 + lds_addr(wm + l15, ks * 32 + lq * 8));
#pragma unroll
      for (int t = 0; t < 4; ++t) {
        bf16x8 bv = *(const bf16x8*)(lsb + lds_addr(wn + t * 16 + l15, ks * 32 + lq * 8));
        accH[t] = __builtin_amdgcn_mfma_f32_16x16x32_bf16(afH, bv, accH[t], 0, 0, 0);
        accT[t] = __builtin_amdgcn_mfma_f32_16x16x32_bf16(afT, bv, accT[t], 0, 0, 0);
      }
    }
  }
#pragma unroll
  for (int t = 0; t < 4; ++t) {
#pragma unroll
    for (int rg = 0; rg < 4; ++rg) {
      int row = r0 + wm + lq * 4 + rg;
      if (row < R_REL) {
        int col = n0 + wn + t * 16 + l15;
        atomicAdd(&P[row * D2 + col], accH[t][rg]);
        atomicAdd(&P[row * D2 + col + 256], accT[t][rg]);
      }
    }
  }
}

__global__ void k_fin(float* __restrict__ P, const float* __restrict__ hsum,
                      const float* __restrict__ tsum) {
  int i = blockIdx.x * 256 + threadIdx.x;
  if (i < R_REL * D2) {
    int r = i >> 9, c = i & 511;
    P[i] = P[i] / (c < 256 ? hsum[r] : tsum[r]);
  }
}

// ---------------- dense attention ----------------
__global__ __launch_bounds__(128) void k_infts(const float* __restrict__ feats,
                                               const float* __restrict__ w1,
                                               const float* __restrict__ w2, const float* __restrict__ b2,
                                               const float* __restrict__ w3, const float* __restrict__ b3,
                                               float* __restrict__ f1, float* __restrict__ f2) {
  __shared__ float fl[512];
  __shared__ float red[128];
  int r = blockIdx.x, t = threadIdx.x;
  for (int i = t; i < 512; i += 128) fl[i] = feats[r * 512 + i];
  __syncthreads();
  float a = 0.f;
  const float* wrow = w1 + (size_t)t * 512;
  for (int k = 0; k < 512; k += 4) {
    float4 v = *(const float4*)(wrow + k);
    a += fl[k + 0] * v.x + fl[k + 1] * v.y + fl[k + 2] * v.z + fl[k + 3] * v.w;
  }
  red[t] = a * w2[t];
  __syncthreads();
  for (int s = 64; s; s >>= 1) { if (t < s) red[t] += red[t + s]; __syncthreads(); }
  if (t == 0) f1[r] = red[0] + b2[0];
  __syncthreads();
  red[t] = a * w3[t];
  __syncthreads();
  for (int s = 64; s; s >>= 1) { if (t < s) red[t] += red[t + s]; __syncthreads(); }
  if (t == 0) f2[r] = red[0] + b3[0];
}

__global__ __launch_bounds__(256) void k_att(const float* __restrict__ adj,
                                             const float* __restrict__ f1,
                                             const float* __restrict__ f2,
                                             const float* __restrict__ vals,
                                             float* __restrict__ dH) {
  __shared__ float coef[512];
  __shared__ float red[256];
  int r = blockIdx.x, t = threadIdx.x;
  float f1r = f1[r];
  float z0, z1 = -1e30f;
  {
    float a = adj[r * 500 + t];
    float z = lrelu(a * (f1r + f2[t]));
    if (!(a > 0.f)) z += -1e9f;
    z0 = z;
  }
  int c1 = t + 256;
  if (c1 < 500) {
    float a = adj[r * 500 + c1];
    float z = lrelu(a * (f1r + f2[c1]));
    if (!(a > 0.f)) z += -1e9f;
    z1 = z;
  }
  red[t] = fmaxf(z0, z1);
  __syncthreads();
  for (int s = 128; s; s >>= 1) { if (t < s) red[t] = fmaxf(red[t], red[t + s]); __syncthreads(); }
  float m = red[0];
  __syncthreads();
  float e0 = expf(z0 - m);
  float e1 = (c1 < 500) ? expf(z1 - m) : 0.f;
  coef[t] = e0;
  coef[c1] = e1;
  red[t] = e0 + e1;
  __syncthreads();
  for (int s = 128; s; s >>= 1) { if (t < s) red[t] += red[t + s]; __syncthreads(); }
  float inv = 1.f / red[0];
  float accA = 0.f, accB = 0.f;
  int dA = t, dB = t + 256;
  for (int c = 0; c < 500; ++c) {
    float cf = coef[c];
    accA += cf * vals[c * 512 + dA];
    accB += cf * vals[c * 512 + dB];
  }
  dH[r * 512 + dA] = fmaxf(accA * inv, 0.f);
  dH[r * 512 + dB] = fmaxf(accB * inv, 0.f);
}

__global__ void k_score(const float* __restrict__ dH, const float* __restrict__ w,
                        const float* __restrict__ b, float* __restrict__ score) {
  int r = blockIdx.x, lane = threadIdx.x;  // block 64
  float a = 0.f;
  for (int k = lane; k < 512; k += 64) a += dH[r * 512 + k] * w[k];
  for (int o = 32; o; o >>= 1) a += __shfl_xor(a, o, 64);
  if (lane == 0) score[r] = a + b[0];
}

// EL[r] = exp(lrelu(score[r]) - gmax); same softmax result as per-row max-subtract
__global__ void k_els(const float* __restrict__ score, float* __restrict__ EL) {
  __shared__ float red[512];
  int t = threadIdx.x;  // block 512
  float v = (t < R_REL) ? lrelu(score[t]) : -3.0e38f;
  red[t] = v;
  __syncthreads();
  for (int s = 256; s; s >>= 1) { if (t < s) red[t] = fmaxf(red[t], red[t + s]); __syncthreads(); }
  float m = red[0];
  EL[t] = (t < R_REL) ? expf(v - m) : 0.f;
}

// ---------------- sparse attention (CSR, wave/row, shfl-broadcast gather) ----------------
__global__ __launch_bounds__(256) void k_spatt(const u16* __restrict__ src,
                                               const float* __restrict__ base,
                                               const int* __restrict__ ptr,
                                               const int* __restrict__ cols,
                                               const int* __restrict__ rels,
                                               const float* __restrict__ EL, float alpha,
                                               u16* __restrict__ outb, float* __restrict__ outf) {
  __shared__ float sEL[512];
  const int tid = threadIdx.x;
  sEL[tid] = EL[tid];
  sEL[tid + 256] = EL[tid + 256];
  __syncthreads();
  const int lane = tid & 63;
  const int e = blockIdx.x * 4 + (tid >> 6);
  int p0 = ptr[e], p1 = ptr[e + 1];
  float a0 = 0.f, a1 = 0.f, a2 = 0.f, a3 = 0.f;
  if (p1 > p0) {
    float s = 0.f;
    for (int j = p0 + lane; j < p1; j += 64) s += sEL[rels[j]];
    for (int o = 32; o; o >>= 1) s += __shfl_xor(s, o, 64);
    float inv = 1.f / s;
    for (int jb = p0; jb < p1; jb += 64) {
      int n = min(64, p1 - jb);
      int cl = 0; float wl = 0.f;
      if (lane < n) { cl = cols[jb + lane]; wl = sEL[rels[jb + lane]] * inv; }
      int jj = 0;
      for (; jj + 4 <= n; jj += 4) {
        int c0 = __shfl(cl, jj), c1 = __shfl(cl, jj + 1), c2 = __shfl(cl, jj + 2), c3 = __shfl(cl, jj + 3);
        float w0 = __shfl(wl, jj), w1 = __shfl(wl, jj + 1), w2 = __shfl(wl, jj + 2), w3 = __shfl(wl, jj + 3);
        uint2 v0 = *(const uint2*)(src + (size_t)c0 * DD + lane * 4);
        uint2 v1 = *(const uint2*)(src + (size_t)c1 * DD + lane * 4);
        uint2 v2 = *(const uint2*)(src + (size_t)c2 * DD + lane * 4);
        uint2 v3 = *(const uint2*)(src + (size_t)c3 * DD + lane * 4);
        a0 += w0 * bf2f((u16)(v0.x & 0xffffu)) + w1 * bf2f((u16)(v1.x & 0xffffu))
            + w2 * bf2f((u16)(v2.x & 0xffffu)) + w3 * bf2f((u16)(v3.x & 0xffffu));
        a1 += w0 * bf2f((u16)(v0.x >> 16)) + w1 * bf2f((u16)(v1.x >> 16))
            + w2 * bf2f((u16)(v2.x >> 16)) + w3 * bf2f((u16)(v3.x >> 16));
        a2 += w0 * bf2f((u16)(v0.y & 0xffffu)) + w1 * bf2f((u16)(v1.y & 0xffffu))
            + w2 * bf2f((u16)(v2.y & 0xffffu)) + w3 * bf2f((u16)(v3.y & 0xffffu));
        a3 += w0 * bf2f((u16)(v0.y >> 16)) + w1 * bf2f((u16)(v1.y >> 16))
            + w2 * bf2f((u16)(v2.y >> 16)) + w3 * bf2f((u16)(v3.y >> 16));
      }
      for (; jj < n; ++jj) {
        int c = __shfl(cl, jj);
        float w = __shfl(wl, jj);
        uint2 v = *(const uint2*)(src + (size_t)c * DD + lane * 4);
        a0 += w * bf2f((u16)(v.x & 0xffffu));
        a1 += w * bf2f((u16)(v.x >> 16));
        a2 += w * bf2f((u16)(v.y & 0xffffu));
        a3 += w * bf2f((u16)(v.y >> 16));
      }
    }
  }
  size_t off = (size_t)e * DD + lane * 4;
  float4 bv = *(const float4*)(base + off);
  float o0 = bv.x + alpha * fmaxf(a0, 0.f);
  float o1 = bv.y + alpha * fmaxf(a1, 0.f);
  float o2 = bv.z + alpha * fmaxf(a2, 0.f);
  float o3 = bv.w + alpha * fmaxf(a3, 0.f);
  uint2 ov;
  ov.x = (u32)f2bf(o0) | ((u32)f2bf(o1) << 16);
  ov.y = (u32)f2bf(o2) | ((u32)f2bf(o3) << 16);
  *(uint2*)(outb + off) = ov;
  if (outf) *(float4*)(outf + off) = make_float4(o0, o1, o2, o3);
}

// ---------------- GCN (CSR, wave/row, shfl-broadcast gather) ----------------
__global__ __launch_bounds__(256) void k_gcn(const u16* __restrict__ src,
                                             const int* __restrict__ ptr,
                                             const int* __restrict__ cols,
                                             const float* __restrict__ vals,
                                             const float* __restrict__ wg,
                                             float* __restrict__ gout) {
  const int lane = threadIdx.x & 63;
  const int e = blockIdx.x * 4 + (threadIdx.x >> 6);
  int p0 = ptr[e], p1 = ptr[e + 1];
  float a0 = 0.f, a1 = 0.f, a2 = 0.f, a3 = 0.f;
  for (int jb = p0; jb < p1; jb += 64) {
    int n = min(64, p1 - jb);
    int cl = 0; float wl = 0.f;
    if (lane < n) { cl = cols[jb + lane]; wl = vals[jb + lane]; }
    int jj = 0;
    for (; jj + 4 <= n; jj += 4) {
      int c0 = __shfl(cl, jj), c1 = __shfl(cl, jj + 1), c2 = __shfl(cl, jj + 2), c3 = __shfl(cl, jj + 3);
      float w0 = __shfl(wl, jj), w1 = __shfl(wl, jj + 1), w2 = __shfl(wl, jj + 2), w3 = __shfl(wl, jj + 3);
      uint2 v0 = *(const uint2*)(src + (size_t)c0 * DD + lane * 4);
      uint2 v1 = *(const uint2*)(src + (size_t)c1 * DD + lane * 4);
      uint2 v2 = *(const uint2*)(src + (size_t)c2 * DD + lane * 4);
      uint2 v3 = *(const uint2*)(src + (size_t)c3 * DD + lane * 4);
      a0 += w0 * bf2f((u16)(v0.x & 0xffffu)) + w1 * bf2f((u16)(v1.x & 0xffffu))
          + w2 * bf2f((u16)(v2.x & 0xffffu)) + w3 * bf2f((u16)(v3.x & 0xffffu));
      a1 += w0 * bf2f((u16)(v0.x >> 16)) + w1 * bf2f((u16)(v1.x >> 16))
          + w2 * bf2f((u16)(v2.x >> 16)) + w3 * bf2f((u16)(v3.x >> 16));
      a2 += w0 * bf2f((u16)(v0.y & 0xffffu)) + w1 * bf2f((u16)(v1.y & 0xffffu))
          + w2 * bf2f((u16)(v2.y & 0xffffu)) + w3 * bf2f((u16)(v3.y & 0xffffu));
      a3 += w0 * bf2f((u16)(v0.y >> 16)) + w1 * bf2f((u16)(v1.y >> 16))
          + w2 * bf2f((u16)(v2.y >> 16)) + w3 * bf2f((u16)(v3.y >> 16));
    }
    for (; jj < n; ++jj) {
      int c = __shfl(cl, jj);
      float w = __shfl(wl, jj);
      uint2 v = *(const uint2*)(src + (size_t)c * DD + lane * 4);
      a0 += w * bf2f((u16)(v.x & 0xffffu));
      a1 += w * bf2f((u16)(v.x >> 16));
      a2 += w * bf2f((u16)(v.y & 0xffffu));
      a3 += w * bf2f((u16)(v.y >> 16));
    }
  }
  int d = lane * 4;
  float4 wv = *(const float4*)(wg + d);
  float4 o = make_float4(fmaxf(a0 * wv.x, 0.f), fmaxf(a1 * wv.y, 0.f),
                         fmaxf(a2 * wv.z, 0.f), fmaxf(a3 * wv.w, 0.f));
  *(float4*)(gout + (size_t)e * DD + d) = o;
}

// ---------------- highway: h = sigmoid(x@K + bg) * g + (1-t) * x ----------------
// xb bf16; KB bf16 precast [256,256]; xf/g f32; in-place xf==outf safe.
__global__ __launch_bounds__(256) void k_hw(const u16* __restrict__ xb,
                                            const float* __restrict__ xf,
                                            const float* __restrict__ g,
                                            const u16* __restrict__ KB,
                                            const float* __restrict__ bg,
                                            float* __restrict__ outf,
                                            u16* __restrict__ outb) {
  __shared__ __align__(16) u16 la[64 * 64];  // [m][k] swizzled
  __shared__ __align__(16) u16 lb[64 * 64];  // [n][k] swizzled
  const int tid = threadIdx.x;
  const int e0 = blockIdx.x * 64;
  const int n0 = blockIdx.y * 64;
  const int lane = tid & 63, wv = tid >> 6;
  const int m0 = wv * 16;
  const int l15 = lane & 15, lq = lane >> 4;
  const int am = tid >> 3, aoct = tid & 7;   // A tiles: rows am, am+32
  const int kp = tid >> 3, nq8 = tid & 7;    // B tile: k-pair 2kp, n-oct nq8
  f32x4 acc[4];
#pragma unroll
  for (int t = 0; t < 4; ++t) acc[t] = (f32x4)0.f;

  for (int kc = 0; kc < 4; ++kc) {
    {
      const u16* pa = xb + (size_t)(e0 + am) * DD + kc * 64 + aoct * 8;
      uint4 va = ld4g(pa, e0 + am < E_ENT);
      *(uint4*)(la + lds_addr(am, aoct * 8)) = va;
      const u16* pa2 = xb + (size_t)(e0 + am + 32) * DD + kc * 64 + aoct * 8;
      uint4 va2 = ld4g(pa2, e0 + am + 32 < E_ENT);
      *(uint4*)(la + lds_addr(am + 32, aoct * 8)) = va2;
      const u16* pb = KB + (size_t)(kc * 64 + 2 * kp) * DD + n0 + nq8 * 8;
      uint4 xk = *(const uint4*)pb;
      uint4 yk = *(const uint4*)(pb + DD);
      pack_store(lb, nq8 * 8, 2 * kp, xk, yk);
    }
    __syncthreads();
#pragma unroll
    for (int ks = 0; ks < 2; ++ks) {
      bf16x8 af = *(const bf16x8*)(la + lds_addr(m0 + l15, ks * 32 + lq * 8));
#pragma unroll
      for (int t = 0; t < 4; ++t) {
        bf16x8 bv = *(const bf16x8*)(lb + lds_addr(t * 16 + l15, ks * 32 + lq * 8));
        acc[t] = __builtin_amdgcn_mfma_f32_16x16x32_bf16(af, bv, acc[t], 0, 0, 0);
      }
    }
    __syncthreads();
  }
#pragma unroll
  for (int t = 0; t < 4; ++t) {
    int col = n0 + t * 16 + l15;
    float bgv = bg[col];
#pragma unroll
    for (int rg = 0; rg < 4; ++rg) {
      int row = e0 + m0 + lq * 4 + rg;
      if (row < E_ENT) {
        float z = acc[t][rg] + bgv;
        float tt = 1.f / (1.f + expf(-z));
        size_t off = (size_t)row * DD + col;
        float hv = tt * g[off] + (1.f - tt) * xf[off];
        outf[off] = hv;
        if (outb) outb[off] = f2bf(hv);
      }
    }
  }
}

// ---------------- host ----------------
extern "C" void kernel_launch(void* const* d_in, const int* in_sizes, int n_in,
                              void* d_out, int out_size, void* d_ws, size_t ws_size,
                              hipStream_t stream) {
  (void)in_sizes; (void)n_in; (void)out_size;
  const float* X0 = (const float*)d_in[0];
  const float* head = (const float*)d_in[1];
  const float* tail = (const float*)d_in[2];
  const float* adj = (const float*)d_in[3];
  const int* erow = (const int*)d_in[4];
  const int* ecol = (const int*)d_in[5];
  const int* erel = (const int*)d_in[6];
  const int* mrow = (const int*)d_in[7];
  const int* mcol = (const int*)d_in[8];
  const float* mval = (const float*)d_in[9];
  const float* w_self1 = (const float*)d_in[10];
  const float* w_self2 = (const float*)d_in[11];
  const float* b_self2 = (const float*)d_in[12];
  const float* w_self3 = (const float*)d_in[13];
  const float* b_self3 = (const float*)d_in[14];
  const float* w_sp1 = (const float*)d_in[15];
  const float* b_sp1 = (const float*)d_in[16];
  const float* w_dual1 = (const float*)d_in[17];
  const float* w_dual2 = (const float*)d_in[18];
  const float* b_dual2 = (const float*)d_in[19];
  const float* w_dual3 = (const float*)d_in[20];
  const float* b_dual3 = (const float*)d_in[21];
  const float* w_sp2 = (const float*)d_in[22];
  const float* b_sp2 = (const float*)d_in[23];
  const float* w_gcn1 = (const float*)d_in[24];
  const float* w_gcn2 = (const float*)d_in[25];
  const float* k_hw1 = (const float*)d_in[26];
  const float* bg_hw1 = (const float*)d_in[27];
  const float* k_hw2 = (const float*)d_in[28];
  const float* bg_hw2 = (const float*)d_in[29];

  char* ws = (char*)d_ws;
  size_t o = 0;
  auto take = [&](size_t bytes) -> char* {
    o = (o + 255) & ~(size_t)255;
    char* p = ws + o;
    o += bytes;
    return p;
  };
  u16* X0B  = (u16*)take((size_t)E_ENT * DD * 2);
  u16* PX1B = (u16*)take((size_t)E_ENT * DD * 2);
  u16* PX2B = (u16*)take((size_t)E_ENT * DD * 2);
  u16* H1B  = (u16*)take((size_t)E_ENT * DD * 2);
  float* PX2F = (float*)take((size_t)E_ENT * DD * 4);  // phase1: HB alias; then pX2, then h1
  float* G    = (float*)take((size_t)E_ENT * DD * 4);  // phase1: TB alias; then gcn out
  float* P1   = (float*)take((size_t)512 * 512 * 4);
  float* P2   = (float*)take((size_t)512 * 512 * 4);
  float* DH1  = (float*)take((size_t)512 * 512 * 4);
  float* DH2  = (float*)take((size_t)512 * 512 * 4);
  float* HS   = (float*)take(1024 * 4);
  float* F1   = (float*)take(512 * 4);
  float* F2   = (float*)take(512 * 4);
  float* SCORE = (float*)take(512 * 4);
  float* EL   = (float*)take(512 * 4);
  u16* KB1 = (u16*)take((size_t)DD * DD * 2);
  u16* KB2 = (u16*)take((size_t)DD * DD * 2);
  int* BSUM = (int*)take(256 * 4);
  int* BOFF = (int*)take(256 * 4);
  int* EPTR = (int*)take((size_t)(E_ENT + 1) * 4);
  int* ECUR = (int*)take((size_t)(E_ENT + 1) * 4);
  int* ECOLS = (int*)take((size_t)NEDGE * 4);
  int* ERELS = (int*)take((size_t)NEDGE * 4);
  int* MPTR = (int*)take((size_t)(E_ENT + 1) * 4);
  int* MCUR = (int*)take((size_t)(E_ENT + 1) * 4);
  int* MCOLS = (int*)take((size_t)NEDGE * 4);
  float* MVALS = (float*)take((size_t)NEDGE * 4);

  // bf16 W buffers alias the f32 buffers used only after round-2 k_wtx
  u16* HB = (u16*)PX2F;  // [E,512] bf16 = 51.2 MB, last read before PX2F first write
  u16* TB = (u16*)G;     // [E,512] bf16, last read before G first write

  if (o > ws_size) {
    hipMemsetAsync(d_out, 0, (size_t)E_ENT * DD * 4, stream);
    return;
  }

  hipMemsetAsync(P1, 0, (size_t)512 * 512 * 4, stream);
  hipMemsetAsync(P2, 0, (size_t)512 * 512 * 4, stream);
  hipMemsetAsync(HS, 0, 1024 * 4, stream);
  hipMemsetAsync(ECUR, 0, (size_t)(E_ENT + 1) * 4, stream);
  hipMemsetAsync(MCUR, 0, (size_t)(E_ENT + 1) * 4, stream);

  const int GE = (NEDGE + 255) / 256;
  const int GB = (E_ENT + 255) / 256;
  const int GW = (E_ENT + 63) / 64;  // 782

  k_cast<<<(E_ENT * DD / 4 + 255) / 256, 256, 0, stream>>>(X0, X0B, E_ENT * DD / 4);
  k_cast<<<64, 256, 0, stream>>>(k_hw1, KB1, DD * DD / 4);
  k_cast<<<64, 256, 0, stream>>>(k_hw2, KB2, DD * DD / 4);
  k_castW<<<GW, 256, 0, stream>>>(head, HB, HS);
  k_castW<<<GW, 256, 0, stream>>>(tail, TB, HS + 512);

  // CSR for edge_row
  k_hist<<<GE, 256, 0, stream>>>(erow, ECUR);
  k_bsum<<<GB, 256, 0, stream>>>(ECUR, BSUM);
  k_scanb<<<1, 256, 0, stream>>>(BSUM, BOFF, GB);
  k_apply<<<GB, 256, 0, stream>>>(ECUR, BOFF, EPTR, ECUR);
  k_scat_e<<<GE, 256, 0, stream>>>(erow, ecol, erel, ECUR, ECOLS, ERELS);
  // CSR for m_row
  k_hist<<<GE, 256, 0, stream>>>(mrow, MCUR);
  k_bsum<<<GB, 256, 0, stream>>>(MCUR, BSUM);
  k_scanb<<<1, 256, 0, stream>>>(BSUM, BOFF, GB);
  k_apply<<<GB, 256, 0, stream>>>(MCUR, BOFF, MPTR, MCUR);
  k_scat_m<<<GE, 256, 0, stream>>>(mrow, mcol, mval, MCUR, MCOLS, MVALS);

  dim3 gw(32, KSPLIT);
  // round 1: dX1 = compute_r(X0)  (head+tail fused)
  k_wtx<<<gw, 256, 0, stream>>>(HB, TB, X0B, P1);
  k_fin<<<1000, 256, 0, stream>>>(P1, HS, HS + 512);
  k_infts<<<500, 128, 0, stream>>>(P1, w_self1, w_self2, b_self2, w_self3, b_self3, F1, F2);
  k_att<<<500, 256, 0, stream>>>(adj, F1, F2, P1, DH1);
  k_score<<<500, 64, 0, stream>>>(DH1, w_sp1, b_sp1, SCORE);
  k_els<<<1, 512, 0, stream>>>(SCORE, EL);
  k_spatt<<<12500, 256, 0, stream>>>(X0B, X0, EPTR, ECOLS, ERELS, EL, 0.1f, PX1B, nullptr);

  // round 2: dX2 = compute_r(pX1)  (head+tail fused)
  k_wtx<<<gw, 256, 0, stream>>>(HB, TB, PX1B, P2);
  k_fin<<<1000, 256, 0, stream>>>(P2, HS, HS + 512);
  k_infts<<<500, 128, 0, stream>>>(P2, w_dual1, w_dual2, b_dual2, w_dual3, b_dual3, F1, F2);
  k_att<<<500, 256, 0, stream>>>(adj, F1, F2, DH1, DH2);
  k_score<<<500, 64, 0, stream>>>(DH2, w_sp2, b_sp2, SCORE);
  k_els<<<1, 512, 0, stream>>>(SCORE, EL);
  k_spatt<<<12500, 256, 0, stream>>>(PX1B, X0, EPTR, ECOLS, ERELS, EL, 0.3f, PX2B, PX2F);

  // g1 = gcn(pX2); h1 = highway(pX2, g1)  (in place on PX2F)
  dim3 gh(782, 4);
  k_gcn<<<12500, 256, 0, stream>>>(PX2B, MPTR, MCOLS, MVALS, w_gcn1, G);
  k_hw<<<gh, 256, 0, stream>>>(PX2B, PX2F, G, KB1, bg_hw1, PX2F, H1B);
  // g2 = gcn(h1); out = highway(h1, g2)
  k_gcn<<<12500, 256, 0, stream>>>(H1B, MPTR, MCOLS, MVALS, w_gcn2, G);
  k_hw<<<gh, 256, 0, stream>>>(H1B, PX2F, G, KB2, bg_hw2, (float*)d_out, nullptr);
}

// Round 2
// 1108.885 us; speedup vs baseline: 1.3225x; 1.0564x over previous
//
#include <hip/hip_runtime.h>
#include <stdint.h>

#define E_ENT 50000
#define R_REL 500
#define NEDGE 500000
#define DD 256
#define D2 512
#define KSPLIT 50
#define KCHUNK 1000

typedef unsigned short u16;
typedef unsigned int u32;
typedef __attribute__((ext_vector_type(8))) short bf16x8;
typedef __attribute__((ext_vector_type(4))) float f32x4;

__device__ __forceinline__ float bf2f(u16 u) {
  union { u32 i; float f; } v; v.i = ((u32)u) << 16; return v.f;
}
__device__ __forceinline__ u16 f2bf(float f) {
  union { float f; u32 i; } v; v.f = f;
  u32 r = v.i + 0x7fffu + ((v.i >> 16) & 1u);
  return (u16)(r >> 16);
}
__device__ __forceinline__ float lrelu(float x) { return x > 0.f ? x : 0.01f * x; }

__device__ __forceinline__ uint4 ld4g(const u16* p, bool v) {
  if (v) return *(const uint4*)p;
  return make_uint4(0u, 0u, 0u, 0u);
}

// Swizzled LDS layout: element (col, e) of a [col][64e] bf16 tile at u16 offset
//   col*64 + (((e>>3) ^ col ^ (col>>3)) & 7)*8 + (e&7)
__device__ __forceinline__ int lds_addr(int col, int e) {
  return col * 64 + ((((e >> 3) ^ col ^ (col >> 3)) & 7) << 3) + (e & 7);
}

// transpose-pack: two e-rows (x = e, y = e+1), 8 cols each -> 8 ds_write_b32
__device__ __forceinline__ void pack_store(u16* __restrict__ lds, int colBase, int e,
                                           const uint4& x, const uint4& y) {
  const u32* xp = (const u32*)&x;
  const u32* yp = (const u32*)&y;
#pragma unroll
  for (int i = 0; i < 4; ++i) {
    u32 xv = xp[i], yv = yp[i];
    u32 lo = (xv & 0xffffu) | (yv << 16);
    u32 hi = (xv >> 16) | (yv & 0xffff0000u);
    int c0 = colBase + 2 * i;
    *(u32*)(lds + lds_addr(c0, e)) = lo;
    *(u32*)(lds + lds_addr(c0 + 1, e)) = hi;
  }
}

// ---------------- f32 -> bf16 cast (4 elems/thread) ----------------
__global__ void k_cast(const float* __restrict__ in, u16* __restrict__ out, int n4) {
  int i = blockIdx.x * 256 + threadIdx.x;
  if (i < n4) {
    float4 v = *(const float4*)(in + (size_t)i * 4);
    uint2 o;
    o.x = (u32)f2bf(v.x) | ((u32)f2bf(v.y) << 16);
    o.y = (u32)f2bf(v.z) | ((u32)f2bf(v.w) << 16);
    *(uint2*)(out + (size_t)i * 4) = o;
  }
}

// ---------------- W [E,500] f32 -> WB [E,512] bf16 (pad 0) + fp32 col sums ----------------
__global__ __launch_bounds__(256) void k_castW(const float* __restrict__ W,
                                               u16* __restrict__ WB,
                                               float* __restrict__ sums) {
  int tid = threadIdx.x;
  int c0 = tid * 2;
  int r0 = blockIdx.x * 64;
  bool valid = c0 < R_REL;
  float s0 = 0.f, s1 = 0.f;
  for (int e = 0; e < 64; ++e) {
    int row = r0 + e;
    if (row >= E_ENT) break;
    u32 out = 0;
    if (valid) {
      float2 v = *(const float2*)(W + (size_t)row * R_REL + c0);
      s0 += v.x; s1 += v.y;
      out = (u32)f2bf(v.x) | ((u32)f2bf(v.y) << 16);
    }
    *(u32*)(WB + (size_t)row * D2 + c0) = out;
  }
  if (valid) {
    atomicAdd(&sums[c0], s0);
    atomicAdd(&sums[c0 + 1], s1);
  }
}

// ---------------- CSR build ----------------
__global__ void k_hist(const int* __restrict__ rows, int* __restrict__ cnt) {
  int i = blockIdx.x * 256 + threadIdx.x;
  if (i < NEDGE) atomicAdd(&cnt[rows[i]], 1);
}

__global__ void k_bsum(const int* __restrict__ cnt, int* __restrict__ bsum) {
  __shared__ int sb[256];
  int t = threadIdx.x, i = blockIdx.x * 256 + t;
  sb[t] = (i < E_ENT) ? cnt[i] : 0;
  __syncthreads();
  for (int s = 128; s; s >>= 1) { if (t < s) sb[t] += sb[t + s]; __syncthreads(); }
  if (t == 0) bsum[blockIdx.x] = sb[0];
}

__global__ void k_scanb(const int* __restrict__ bsum, int* __restrict__ boff, int nb) {
  __shared__ int sb[256];
  int t = threadIdx.x;
  int v = (t < nb) ? bsum[t] : 0;
  sb[t] = v;
  __syncthreads();
  for (int o = 1; o < 256; o <<= 1) {
    int x = (t >= o) ? sb[t - o] : 0;
    __syncthreads();
    sb[t] += x;
    __syncthreads();
  }
  if (t < nb) boff[t] = sb[t] - v;
}

__global__ void k_apply(const int* __restrict__ cnt, const int* __restrict__ boff,
                        int* __restrict__ ptr, int* __restrict__ cur) {
  __shared__ int sb[256];
  int t = threadIdx.x, b = blockIdx.x, i = b * 256 + t;
  int v = (i < E_ENT) ? cnt[i] : 0;
  sb[t] = v;
  __syncthreads();
  for (int o = 1; o < 256; o <<= 1) {
    int x = (t >= o) ? sb[t - o] : 0;
    __syncthreads();
    sb[t] += x;
    __syncthreads();
  }
  if (i < E_ENT) { int ex = boff[b] + sb[t] - v; ptr[i] = ex; cur[i] = ex; }
  if (b == 0 && t == 0) ptr[E_ENT] = NEDGE;
}

__global__ void k_scat_e(const int* __restrict__ rows, const int* __restrict__ cols,
                         const int* __restrict__ rels, int* __restrict__ cur,
                         int* __restrict__ cs, int* __restrict__ rs) {
  int i = blockIdx.x * 256 + threadIdx.x;
  if (i < NEDGE) {
    int p = atomicAdd(&cur[rows[i]], 1);
    cs[p] = cols[i];
    rs[p] = rels[i];
  }
}

__global__ void k_scat_m(const int* __restrict__ rows, const int* __restrict__ cols,
                         const float* __restrict__ vals, int* __restrict__ cur,
                         int* __restrict__ cs, float* __restrict__ vs) {
  int i = blockIdx.x * 256 + threadIdx.x;
  if (i < NEDGE) {
    int p = atomicAdd(&cur[rows[i]], 1);
    cs[p] = cols[i];
    vs[p] = vals[i];
  }
}

// ---------------- fused [HB|TB]^T @ X (M=2x500,K=50000,N=256), split-K, MFMA ------------
// HB/TB: bf16 [E,512]; XB: bf16 [E,256]. flat grid 1600, XCD-swizzled so each
// K-chunk's 32 tiles (16mt x 2nt) run on ONE XCD -> chunk W/XB slices L2-resident.
__device__ __forceinline__ void wtx_load(const u16* __restrict__ WSel, const u16* __restrict__ XB,
                                         int eb, int e_end, int r0, int n0,
                                         int ap, int aq, int ep0, int ep1, int nq,
                                         uint4& a0, uint4& a1, uint4& b00, uint4& b01,
                                         uint4& b10, uint4& b11) {
  int ee = e_end - eb;
  const u16* p = WSel + (size_t)(eb + 2 * ap) * D2 + r0 + aq * 8;
  a0 = ld4g(p, 2 * ap < ee);
  a1 = ld4g(p + D2, 2 * ap + 1 < ee);
  const u16* q0 = XB + (size_t)(eb + 2 * ep0) * DD + n0 + nq * 8;
  b00 = ld4g(q0, 2 * ep0 < ee);
  b01 = ld4g(q0 + DD, 2 * ep0 + 1 < ee);
  const u16* q1 = XB + (size_t)(eb + 2 * ep1) * DD + n0 + nq * 8;
  b10 = ld4g(q1, 2 * ep1 < ee);
  b11 = ld4g(q1 + DD, 2 * ep1 + 1 < ee);
}

__global__ __launch_bounds__(256) void k_wtx(const u16* __restrict__ HB,
                                             const u16* __restrict__ TB,
                                             const u16* __restrict__ XB,
                                             float* __restrict__ P) {
  __shared__ __align__(16) u16 lsa2[2 * 32 * 64];  // [H|T] A-tiles, swizzled
  __shared__ __align__(16) u16 lsb[128 * 64];      // B-tile, swizzled
  const int tid = threadIdx.x;
  // XCD swizzle: 1600 blocks, round-robin dispatch (bid%8 = XCD). Give XCD k the
  // 200 consecutive logical tiles [200k, 200k+200) -> whole K-chunks per XCD.
  const int bid = blockIdx.x;
  const int swz = (bid & 7) * 200 + (bid >> 3);
  const int mtnt = swz & 31;
  const int mt = mtnt >> 1, nt = mtnt & 1;
  const int chunk = swz >> 5;
  const int r0 = mt * 32, n0 = nt * 128;
  const int lane = tid & 63, wv = tid >> 6;
  const int wm = (wv & 1) * 16, wn = (wv >> 1) * 64;
  const int l15 = lane & 15, lq = lane >> 4;
  const int ap = (tid & 127) >> 2, aq = tid & 3;  // A tile: e-pair, r-oct (per half)
  const int ep0 = tid >> 4, nq = tid & 15;        // B tiles: e-pairs ep0, ep0+16
  const int ep1 = ep0 + 16;
  const u16* WSel = (tid < 128) ? HB : TB;
  u16* lsaSel = lsa2 + (tid >> 7) * (32 * 64);
  const int e_begin = chunk * KCHUNK;
  const int e_end = min(e_begin + KCHUNK, E_ENT);
  const int iters = (e_end - e_begin + 63) >> 6;

  f32x4 accH[4], accT[4];
#pragma unroll
  for (int t = 0; t < 4; ++t) { accH[t] = (f32x4)0.f; accT[t] = (f32x4)0.f; }

  uint4 a0, a1, b00, b01, b10, b11;
  wtx_load(WSel, XB, e_begin, e_end, r0, n0, ap, aq, ep0, ep1, nq, a0, a1, b00, b01, b10, b11);

  int eb = e_begin;
  for (int it = 0; it < iters; ++it) {
    __syncthreads();
    pack_store(lsaSel, aq * 8, 2 * ap, a0, a1);
    pack_store(lsb, nq * 8, 2 * ep0, b00, b01);
    pack_store(lsb, nq * 8, 2 * ep1, b10, b11);
    __syncthreads();
    eb += 64;
    if (it + 1 < iters)
      wtx_load(WSel, XB, eb, e_end, r0, n0, ap, aq, ep0, ep1, nq, a0, a1, b00, b01, b10, b11);
#pragma unroll
    for (int ks = 0; ks < 2; ++ks) {
      bf16x8 afH = *(const bf16x8*)(lsa2 + lds_addr(wm + l15, ks * 32 + lq * 8));
      bf16x8 afT = *(const bf16x8*)(lsa2 + 32 * 64 + lds_addr(wm + l15, ks * 32 + lq * 8));
#pragma unroll
      for (int t = 0; t < 4; ++t) {
        bf16x8 bv = *(const bf16x8*)(lsb + lds_addr(wn + t * 16 + l15, ks * 32 + lq * 8));
        accH[t] = __builtin_amdgcn_mfma_f32_16x16x32_bf16(afH, bv, accH[t], 0, 0, 0);
        accT[t] = __builtin_amdgcn_mfma_f32_16x16x32_bf16(afT, bv, accT[t], 0, 0, 0);
      }
    }
  }
#pragma unroll
  for (int t = 0; t < 4; ++t) {
#pragma unroll
    for (int rg = 0; rg < 4; ++rg) {
      int row = r0 + wm + lq * 4 + rg;
      if (row < R_REL) {
        int col = n0 + wn + t * 16 + l15;
        atomicAdd(&P[row * D2 + col], accH[t][rg]);
        atomicAdd(&P[row * D2 + col + 256], accT[t][rg]);
      }
    }
  }
}

__global__ void k_fin(float* __restrict__ P, const float* __restrict__ hsum,
                      const float* __restrict__ tsum) {
  int i = blockIdx.x * 256 + threadIdx.x;
  if (i < R_REL * D2) {
    int r = i >> 9, c = i & 511;
    P[i] = P[i] / (c < 256 ? hsum[r] : tsum[r]);
  }
}

// ---------------- dense attention ----------------
__global__ __launch_bounds__(128) void k_infts(const float* __restrict__ feats,
                                               const float* __restrict__ w1,
                                               const float* __restrict__ w2, const float* __restrict__ b2,
                                               const float* __restrict__ w3, const float* __restrict__ b3,
                                               float* __restrict__ f1, float* __restrict__ f2) {
  __shared__ float fl[512];
  __shared__ float red[128];
  int r = blockIdx.x, t = threadIdx.x;
  for (int i = t; i < 512; i += 128) fl[i] = feats[r * 512 + i];
  __syncthreads();
  float a = 0.f;
  const float* wrow = w1 + (size_t)t * 512;
  for (int k = 0; k < 512; k += 4) {
    float4 v = *(const float4*)(wrow + k);
    a += fl[k + 0] * v.x + fl[k + 1] * v.y + fl[k + 2] * v.z + fl[k + 3] * v.w;
  }
  red[t] = a * w2[t];
  __syncthreads();
  for (int s = 64; s; s >>= 1) { if (t < s) red[t] += red[t + s]; __syncthreads(); }
  if (t == 0) f1[r] = red[0] + b2[0];
  __syncthreads();
  red[t] = a * w3[t];
  __syncthreads();
  for (int s = 64; s; s >>= 1) { if (t < s) red[t] += red[t + s]; __syncthreads(); }
  if (t == 0) f2[r] = red[0] + b3[0];
}

__global__ __launch_bounds__(256) void k_att(const float* __restrict__ adj,
                                             const float* __restrict__ f1,
                                             const float* __restrict__ f2,
                                             const float* __restrict__ vals,
                                             float* __restrict__ dH) {
  __shared__ float coef[512];
  __shared__ float red[256];
  int r = blockIdx.x, t = threadIdx.x;
  float f1r = f1[r];
  float z0, z1 = -1e30f;
  {
    float a = adj[r * 500 + t];
    float z = lrelu(a * (f1r + f2[t]));
    if (!(a > 0.f)) z += -1e9f;
    z0 = z;
  }
  int c1 = t + 256;
  if (c1 < 500) {
    float a = adj[r * 500 + c1];
    float z = lrelu(a * (f1r + f2[c1]));
    if (!(a > 0.f)) z += -1e9f;
    z1 = z;
  }
  red[t] = fmaxf(z0, z1);
  __syncthreads();
  for (int s = 128; s; s >>= 1) { if (t < s) red[t] = fmaxf(red[t], red[t + s]); __syncthreads(); }
  float m = red[0];
  __syncthreads();
  float e0 = expf(z0 - m);
  float e1 = (c1 < 500) ? expf(z1 - m) : 0.f;
  coef[t] = e0;
  coef[c1] = e1;
  red[t] = e0 + e1;
  __syncthreads();
  for (int s = 128; s; s >>= 1) { if (t < s) red[t] += red[t + s]; __syncthreads(); }
  float inv = 1.f / red[0];
  float accA = 0.f, accB = 0.f;
  int dA = t, dB = t + 256;
  for (int c = 0; c < 500; ++c) {
    float cf = coef[c];
    accA += cf * vals[c * 512 + dA];
    accB += cf * vals[c * 512 + dB];
  }
  dH[r * 512 + dA] = fmaxf(accA * inv, 0.f);
  dH[r * 512 + dB] = fmaxf(accB * inv, 0.f);
}

__global__ void k_score(const float* __restrict__ dH, const float* __restrict__ w,
                        const float* __restrict__ b, float* __restrict__ score) {
  int r = blockIdx.x, lane = threadIdx.x;  // block 64
  float a = 0.f;
  for (int k = lane; k < 512; k += 64) a += dH[r * 512 + k] * w[k];
  for (int o = 32; o; o >>= 1) a += __shfl_xor(a, o, 64);
  if (lane == 0) score[r] = a + b[0];
}

// EL[r] = exp(lrelu(score[r]) - gmax); same softmax result as per-row max-subtract
__global__ void k_els(const float* __restrict__ score, float* __restrict__ EL) {
  __shared__ float red[512];
  int t = threadIdx.x;  // block 512
  float v = (t < R_REL) ? lrelu(score[t]) : -3.0e38f;
  red[t] = v;
  __syncthreads();
  for (int s = 256; s; s >>= 1) { if (t < s) red[t] = fmaxf(red[t], red[t + s]); __syncthreads(); }
  float m = red[0];
  EL[t] = (t < R_REL) ? expf(v - m) : 0.f;
}

// ---------------- sparse attention (CSR, wave/row, shfl-broadcast gather) ----------------
__global__ __launch_bounds__(256) void k_spatt(const u16* __restrict__ src,
                                               const float* __restrict__ base,
                                               const int* __restrict__ ptr,
                                               const int* __restrict__ cols,
                                               const int* __restrict__ rels,
                                               const float* __restrict__ EL, float alpha,
                                               u16* __restrict__ outb, float* __restrict__ outf) {
  __shared__ float sEL[512];
  const int tid = threadIdx.x;
  sEL[tid] = EL[tid];
  sEL[tid + 256] = EL[tid + 256];
  __syncthreads();
  const int lane = tid & 63;
  const int e = blockIdx.x * 4 + (tid >> 6);
  int p0 = ptr[e], p1 = ptr[e + 1];
  float a0 = 0.f, a1 = 0.f, a2 = 0.f, a3 = 0.f;
  if (p1 > p0) {
    float s = 0.f;
    for (int j = p0 + lane; j < p1; j += 64) s += sEL[rels[j]];
    for (int o = 32; o; o >>= 1) s += __shfl_xor(s, o, 64);
    float inv = 1.f / s;
    for (int jb = p0; jb < p1; jb += 64) {
      int n = min(64, p1 - jb);
      int cl = 0; float wl = 0.f;
      if (lane < n) { cl = cols[jb + lane]; wl = sEL[rels[jb + lane]] * inv; }
      int jj = 0;
      for (; jj + 4 <= n; jj += 4) {
        int c0 = __shfl(cl, jj), c1 = __shfl(cl, jj + 1), c2 = __shfl(cl, jj + 2), c3 = __shfl(cl, jj + 3);
        float w0 = __shfl(wl, jj), w1 = __shfl(wl, jj + 1), w2 = __shfl(wl, jj + 2), w3 = __shfl(wl, jj + 3);
        uint2 v0 = *(const uint2*)(src + (size_t)c0 * DD + lane * 4);
        uint2 v1 = *(const uint2*)(src + (size_t)c1 * DD + lane * 4);
        uint2 v2 = *(const uint2*)(src + (size_t)c2 * DD + lane * 4);
        uint2 v3 = *(const uint2*)(src + (size_t)c3 * DD + lane * 4);
        a0 += w0 * bf2f((u16)(v0.x & 0xffffu)) + w1 * bf2f((u16)(v1.x & 0xffffu))
            + w2 * bf2f((u16)(v2.x & 0xffffu)) + w3 * bf2f((u16)(v3.x & 0xffffu));
        a1 += w0 * bf2f((u16)(v0.x >> 16)) + w1 * bf2f((u16)(v1.x >> 16))
            + w2 * bf2f((u16)(v2.x >> 16)) + w3 * bf2f((u16)(v3.x >> 16));
        a2 += w0 * bf2f((u16)(v0.y & 0xffffu)) + w1 * bf2f((u16)(v1.y & 0xffffu))
            + w2 * bf2f((u16)(v2.y & 0xffffu)) + w3 * bf2f((u16)(v3.y & 0xffffu));
        a3 += w0 * bf2f((u16)(v0.y >> 16)) + w1 * bf2f((u16)(v1.y >> 16))
            + w2 * bf2f((u16)(v2.y >> 16)) + w3 * bf2f((u16)(v3.y >> 16));
      }
      for (; jj < n; ++jj) {
        int c = __shfl(cl, jj);
        float w = __shfl(wl, jj);
        uint2 v = *(const uint2*)(src + (size_t)c * DD + lane * 4);
        a0 += w * bf2f((u16)(v.x & 0xffffu));
        a1 += w * bf2f((u16)(v.x >> 16));
        a2 += w * bf2f((u16)(v.y & 0xffffu));
        a3 += w * bf2f((u16)(v.y >> 16));
      }
    }
  }
  size_t off = (size_t)e * DD + lane * 4;
  float4 bv = *(const float4*)(base + off);
  float o0 = bv.x + alpha * fmaxf(a0, 0.f);
  float o1 = bv.y + alpha * fmaxf(a1, 0.f);
  float o2 = bv.z + alpha * fmaxf(a2, 0.f);
  float o3 = bv.w + alpha * fmaxf(a3, 0.f);
  uint2 ov;
  ov.x = (u32)f2bf(o0) | ((u32)f2bf(o1) << 16);
  ov.y = (u32)f2bf(o2) | ((u32)f2bf(o3) << 16);
  *(uint2*)(outb + off) = ov;
  if (outf) *(float4*)(outf + off) = make_float4(o0, o1, o2, o3);
}

// ---------------- GCN (CSR, wave/row, shfl-broadcast gather) ----------------
__global__ __launch_bounds__(256) void k_gcn(const u16* __restrict__ src,
                                             const int* __restrict__ ptr,
                                             const int* __restrict__ cols,
                                             const float* __restrict__ vals,
                                             const float* __restrict__ wg,
                                             float* __restrict__ gout) {
  const int lane = threadIdx.x & 63;
  const int e = blockIdx.x * 4 + (threadIdx.x >> 6);
  int p0 = ptr[e], p1 = ptr[e + 1];
  float a0 = 0.f, a1 = 0.f, a2 = 0.f, a3 = 0.f;
  for (int jb = p0; jb < p1; jb += 64) {
    int n = min(64, p1 - jb);
    int cl = 0; float wl = 0.f;
    if (lane < n) { cl = cols[jb + lane]; wl = vals[jb + lane]; }
    int jj = 0;
    for (; jj + 4 <= n; jj += 4) {
      int c0 = __shfl(cl, jj), c1 = __shfl(cl, jj + 1), c2 = __shfl(cl, jj + 2), c3 = __shfl(cl, jj + 3);
      float w0 = __shfl(wl, jj), w1 = __shfl(wl, jj + 1), w2 = __shfl(wl, jj + 2), w3 = __shfl(wl, jj + 3);
      uint2 v0 = *(const uint2*)(src + (size_t)c0 * DD + lane * 4);
      uint2 v1 = *(const uint2*)(src + (size_t)c1 * DD + lane * 4);
      uint2 v2 = *(const uint2*)(src + (size_t)c2 * DD + lane * 4);
      uint2 v3 = *(const uint2*)(src + (size_t)c3 * DD + lane * 4);
      a0 += w0 * bf2f((u16)(v0.x & 0xffffu)) + w1 * bf2f((u16)(v1.x & 0xffffu))
          + w2 * bf2f((u16)(v2.x & 0xffffu)) + w3 * bf2f((u16)(v3.x & 0xffffu));
      a1 += w0 * bf2f((u16)(v0.x >> 16)) + w1 * bf2f((u16)(v1.x >> 16))
          + w2 * bf2f((u16)(v2.x >> 16)) + w3 * bf2f((u16)(v3.x >> 16));
      a2 += w0 * bf2f((u16)(v0.y & 0xffffu)) + w1 * bf2f((u16)(v1.y & 0xffffu))
          + w2 * bf2f((u16)(v2.y & 0xffffu)) + w3 * bf2f((u16)(v3.y & 0xffffu));
      a3 += w0 * bf2f((u16)(v0.y >> 16)) + w1 * bf2f((u16)(v1.y >> 16))
          + w2 * bf2f((u16)(v2.y >> 16)) + w3 * bf2f((u16)(v3.y >> 16));
    }
    for (; jj < n; ++jj) {
      int c = __shfl(cl, jj);
      float w = __shfl(wl, jj);
      uint2 v = *(const uint2*)(src + (size_t)c * DD + lane * 4);
      a0 += w * bf2f((u16)(v.x & 0xffffu));
      a1 += w * bf2f((u16)(v.x >> 16));
      a2 += w * bf2f((u16)(v.y & 0xffffu));
      a3 += w * bf2f((u16)(v.y >> 16));
    }
  }
  int d = lane * 4;
  float4 wv = *(const float4*)(wg + d);
  float4 o = make_float4(fmaxf(a0 * wv.x, 0.f), fmaxf(a1 * wv.y, 0.f),
                         fmaxf(a2 * wv.z, 0.f), fmaxf(a3 * wv.w, 0.f));
  *(float4*)(gout + (size_t)e * DD + d) = o;
}

// ---------------- highway: h = sigmoid(x@K + bg) * g + (1-t) * x ----------------
// xb bf16; KB bf16 precast [256,256]; xf/g f32; in-place xf==outf safe.
// flat grid 3128, XCD-swizzled: 4 n-siblings of an e-tile stay on one XCD (xb reuse).
__global__ __launch_bounds__(256) void k_hw(const u16* __restrict__ xb,
                                            const float* __restrict__ xf,
                                            const float* __restrict__ g,
                                            const u16* __restrict__ KB,
                                            const float* __restrict__ bg,
                                            float* __restrict__ outf,
                                            u16* __restrict__ outb) {
  __shared__ __align__(16) u16 la[64 * 64];  // [m][k] swizzled
  __shared__ __align__(16) u16 lb[64 * 64];  // [n][k] swizzled
  const int tid = threadIdx.x;
  const int bid = blockIdx.x;
  const int swz = (bid & 7) * 391 + (bid >> 3);  // 3128 = 8 * 391, bijective
  const int e0 = (swz >> 2) * 64;
  const int n0 = (swz & 3) * 64;
  const int lane = tid & 63, wv = tid >> 6;
  const int m0 = wv * 16;
  const int l15 = lane & 15, lq = lane >> 4;
  const int am = tid >> 3, aoct = tid & 7;   // A tiles: rows am, am+32
  const int kp = tid >> 3, nq8 = tid & 7;    // B tile: k-pair 2kp, n-oct nq8
  f32x4 acc[4];
#pragma unroll
  for (int t = 0; t < 4; ++t) acc[t] = (f32x4)0.f;

  for (int kc = 0; kc < 4; ++kc) {
    {
      const u16* pa = xb + (size_t)(e0 + am) * DD + kc * 64 + aoct * 8;
      uint4 va = ld4g(pa, e0 + am < E_ENT);
      *(uint4*)(la + lds_addr(am, aoct * 8)) = va;
      const u16* pa2 = xb + (size_t)(e0 + am + 32) * DD + kc * 64 + aoct * 8;
      uint4 va2 = ld4g(pa2, e0 + am + 32 < E_ENT);
      *(uint4*)(la + lds_addr(am + 32, aoct * 8)) = va2;
      const u16* pb = KB + (size_t)(kc * 64 + 2 * kp) * DD + n0 + nq8 * 8;
      uint4 xk = *(const uint4*)pb;
      uint4 yk = *(const uint4*)(pb + DD);
      pack_store(lb, nq8 * 8, 2 * kp, xk, yk);
    }
    __syncthreads();
#pragma unroll
    for (int ks = 0; ks < 2; ++ks) {
      bf16x8 af = *(const bf16x8*)(la + lds_addr(m0 + l15, ks * 32 + lq * 8));
#pragma unroll
      for (int t = 0; t < 4; ++t) {
        bf16x8 bv = *(const bf16x8*)(lb + lds_addr(t * 16 + l15, ks * 32 + lq * 8));
        acc[t] = __builtin_amdgcn_mfma_f32_16x16x32_bf16(af, bv, acc[t], 0, 0, 0);
      }
    }
    __syncthreads();
  }
#pragma unroll
  for (int t = 0; t < 4; ++t) {
    int col = n0 + t * 16 + l15;
    float bgv = bg[col];
#pragma unroll
    for (int rg = 0; rg < 4; ++rg) {
      int row = e0 + m0 + lq * 4 + rg;
      if (row < E_ENT) {
        float z = acc[t][rg] + bgv;
        float tt = 1.f / (1.f + expf(-z));
        size_t off = (size_t)row * DD + col;
        float hv = tt * g[off] + (1.f - tt) * xf[off];
        outf[off] = hv;
        if (outb) outb[off] = f2bf(hv);
      }
    }
  }
}

// ---------------- host ----------------
extern "C" void kernel_launch(void* const* d_in, const int* in_sizes, int n_in,
                              void* d_out, int out_size, void* d_ws, size_t ws_size,
                              hipStream_t stream) {
  (void)in_sizes; (void)n_in; (void)out_size;
  const float* X0 = (const float*)d_in[0];
  const float* head = (const float*)d_in[1];
  const float* tail = (const float*)d_in[2];
  const float* adj = (const float*)d_in[3];
  const int* erow = (const int*)d_in[4];
  const int* ecol = (const int*)d_in[5];
  const int* erel = (const int*)d_in[6];
  const int* mrow = (const int*)d_in[7];
  const int* mcol = (const int*)d_in[8];
  const float* mval = (const float*)d_in[9];
  const float* w_self1 = (const float*)d_in[10];
  const float* w_self2 = (const float*)d_in[11];
  const float* b_self2 = (const float*)d_in[12];
  const float* w_self3 = (const float*)d_in[13];
  const float* b_self3 = (const float*)d_in[14];
  const float* w_sp1 = (const float*)d_in[15];
  const float* b_sp1 = (const float*)d_in[16];
  const float* w_dual1 = (const float*)d_in[17];
  const float* w_dual2 = (const float*)d_in[18];
  const float* b_dual2 = (const float*)d_in[19];
  const float* w_dual3 = (const float*)d_in[20];
  const float* b_dual3 = (const float*)d_in[21];
  const float* w_sp2 = (const float*)d_in[22];
  const float* b_sp2 = (const float*)d_in[23];
  const float* w_gcn1 = (const float*)d_in[24];
  const float* w_gcn2 = (const float*)d_in[25];
  const float* k_hw1 = (const float*)d_in[26];
  const float* bg_hw1 = (const float*)d_in[27];
  const float* k_hw2 = (const float*)d_in[28];
  const float* bg_hw2 = (const float*)d_in[29];

  char* ws = (char*)d_ws;
  size_t o = 0;
  auto take = [&](size_t bytes) -> char* {
    o = (o + 255) & ~(size_t)255;
    char* p = ws + o;
    o += bytes;
    return p;
  };
  u16* X0B  = (u16*)take((size_t)E_ENT * DD * 2);
  u16* PX1B = (u16*)take((size_t)E_ENT * DD * 2);
  u16* PX2B = (u16*)take((size_t)E_ENT * DD * 2);
  u16* H1B  = (u16*)take((size_t)E_ENT * DD * 2);
  float* PX2F = (float*)take((size_t)E_ENT * DD * 4);  // phase1: HB alias; then pX2, then h1
  float* G    = (float*)take((size_t)E_ENT * DD * 4);  // phase1: TB alias; then gcn out
  float* P1   = (float*)take((size_t)512 * 512 * 4);
  float* P2   = (float*)take((size_t)512 * 512 * 4);
  float* DH1  = (float*)take((size_t)512 * 512 * 4);
  float* DH2  = (float*)take((size_t)512 * 512 * 4);
  float* HS   = (float*)take(1024 * 4);
  float* F1   = (float*)take(512 * 4);
  float* F2   = (float*)take(512 * 4);
  float* SCORE = (float*)take(512 * 4);
  float* EL   = (float*)take(512 * 4);
  u16* KB1 = (u16*)take((size_t)DD * DD * 2);
  u16* KB2 = (u16*)take((size_t)DD * DD * 2);
  int* BSUM = (int*)take(256 * 4);
  int* BOFF = (int*)take(256 * 4);
  int* EPTR = (int*)take((size_t)(E_ENT + 1) * 4);
  int* ECUR = (int*)take((size_t)(E_ENT + 1) * 4);
  int* ECOLS = (int*)take((size_t)NEDGE * 4);
  int* ERELS = (int*)take((size_t)NEDGE * 4);
  int* MPTR = (int*)take((size_t)(E_ENT + 1) * 4);
  int* MCUR = (int*)take((size_t)(E_ENT + 1) * 4);
  int* MCOLS = (int*)take((size_t)NEDGE * 4);
  float* MVALS = (float*)take((size_t)NEDGE * 4);

  // bf16 W buffers alias the f32 buffers used only after round-2 k_wtx
  u16* HB = (u16*)PX2F;  // [E,512] bf16 = 51.2 MB, last read before PX2F first write
  u16* TB = (u16*)G;     // [E,512] bf16, last read before G first write

  if (o > ws_size) {
    hipMemsetAsync(d_out, 0, (size_t)E_ENT * DD * 4, stream);
    return;
  }

  hipMemsetAsync(P1, 0, (size_t)512 * 512 * 4, stream);
  hipMemsetAsync(P2, 0, (size_t)512 * 512 * 4, stream);
  hipMemsetAsync(HS, 0, 1024 * 4, stream);
  hipMemsetAsync(ECUR, 0, (size_t)(E_ENT + 1) * 4, stream);
  hipMemsetAsync(MCUR, 0, (size_t)(E_ENT + 1) * 4, stream);

  const int GE = (NEDGE + 255) / 256;
  const int GB = (E_ENT + 255) / 256;
  const int GW = (E_ENT + 63) / 64;  // 782

  k_cast<<<(E_ENT * DD / 4 + 255) / 256, 256, 0, stream>>>(X0, X0B, E_ENT * DD / 4);
  k_cast<<<64, 256, 0, stream>>>(k_hw1, KB1, DD * DD / 4);
  k_cast<<<64, 256, 0, stream>>>(k_hw2, KB2, DD * DD / 4);
  k_castW<<<GW, 256, 0, stream>>>(head, HB, HS);
  k_castW<<<GW, 256, 0, stream>>>(tail, TB, HS + 512);

  // CSR for edge_row
  k_hist<<<GE, 256, 0, stream>>>(erow, ECUR);
  k_bsum<<<GB, 256, 0, stream>>>(ECUR, BSUM);
  k_scanb<<<1, 256, 0, stream>>>(BSUM, BOFF, GB);
  k_apply<<<GB, 256, 0, stream>>>(ECUR, BOFF, EPTR, ECUR);
  k_scat_e<<<GE, 256, 0, stream>>>(erow, ecol, erel, ECUR, ECOLS, ERELS);
  // CSR for m_row
  k_hist<<<GE, 256, 0, stream>>>(mrow, MCUR);
  k_bsum<<<GB, 256, 0, stream>>>(MCUR, BSUM);
  k_scanb<<<1, 256, 0, stream>>>(BSUM, BOFF, GB);
  k_apply<<<GB, 256, 0, stream>>>(MCUR, BOFF, MPTR, MCUR);
  k_scat_m<<<GE, 256, 0, stream>>>(mrow, mcol, mval, MCUR, MCOLS, MVALS);

  // round 1: dX1 = compute_r(X0)  (head+tail fused, XCD-swizzled flat grid)
  k_wtx<<<32 * KSPLIT, 256, 0, stream>>>(HB, TB, X0B, P1);
  k_fin<<<1000, 256, 0, stream>>>(P1, HS, HS + 512);
  k_infts<<<500, 128, 0, stream>>>(P1, w_self1, w_self2, b_self2, w_self3, b_self3, F1, F2);
  k_att<<<500, 256, 0, stream>>>(adj, F1, F2, P1, DH1);
  k_score<<<500, 64, 0, stream>>>(DH1, w_sp1, b_sp1, SCORE);
  k_els<<<1, 512, 0, stream>>>(SCORE, EL);
  k_spatt<<<12500, 256, 0, stream>>>(X0B, X0, EPTR, ECOLS, ERELS, EL, 0.1f, PX1B, nullptr);

  // round 2: dX2 = compute_r(pX1)  (head+tail fused)
  k_wtx<<<32 * KSPLIT, 256, 0, stream>>>(HB, TB, PX1B, P2);
  k_fin<<<1000, 256, 0, stream>>>(P2, HS, HS + 512);
  k_infts<<<500, 128, 0, stream>>>(P2, w_dual1, w_dual2, b_dual2, w_dual3, b_dual3, F1, F2);
  k_att<<<500, 256, 0, stream>>>(adj, F1, F2, DH1, DH2);
  k_score<<<500, 64, 0, stream>>>(DH2, w_sp2, b_sp2, SCORE);
  k_els<<<1, 512, 0, stream>>>(SCORE, EL);
  k_spatt<<<12500, 256, 0, stream>>>(PX1B, X0, EPTR, ECOLS, ERELS, EL, 0.3f, PX2B, PX2F);

  // g1 = gcn(pX2); h1 = highway(pX2, g1)  (in place on PX2F)
  k_gcn<<<12500, 256, 0, stream>>>(PX2B, MPTR, MCOLS, MVALS, w_gcn1, G);
  k_hw<<<782 * 4, 256, 0, stream>>>(PX2B, PX2F, G, KB1, bg_hw1, PX2F, H1B);
  // g2 = gcn(h1); out = highway(h1, g2)
  k_gcn<<<12500, 256, 0, stream>>>(H1B, MPTR, MCOLS, MVALS, w_gcn2, G);
  k_hw<<<782 * 4, 256, 0, stream>>>(H1B, PX2F, G, KB2, bg_hw2, (float*)d_out, nullptr);
}

// Round 3
// 1010.822 us; speedup vs baseline: 1.4508x; 1.0970x over previous
//
#include <hip/hip_runtime.h>
#include <stdint.h>

#define E_ENT 50000
#define R_REL 500
#define NEDGE 500000
#define DD 256
#define D2 512
#define KSPLIT 50
#define KCHUNK 1000

typedef unsigned short u16;
typedef unsigned int u32;
typedef __attribute__((ext_vector_type(8))) short bf16x8;
typedef __attribute__((ext_vector_type(4))) float f32x4;

__device__ __forceinline__ float bf2f(u16 u) {
  union { u32 i; float f; } v; v.i = ((u32)u) << 16; return v.f;
}
__device__ __forceinline__ u16 f2bf(float f) {
  union { float f; u32 i; } v; v.f = f;
  u32 r = v.i + 0x7fffu + ((v.i >> 16) & 1u);
  return (u16)(r >> 16);
}
__device__ __forceinline__ float lrelu(float x) { return x > 0.f ? x : 0.01f * x; }

__device__ __forceinline__ uint4 ld4g(const u16* p, bool v) {
  if (v) return *(const uint4*)p;
  return make_uint4(0u, 0u, 0u, 0u);
}
__device__ __forceinline__ float4 ldf4(const float* p, bool v) {
  if (v) return *(const float4*)p;
  return make_float4(0.f, 0.f, 0.f, 0.f);
}

// pack 8 f32 (x = cols 0..3, y = cols 4..7) into 8 bf16 (RTNE)
__device__ __forceinline__ uint4 pk4(const float4& x, const float4& y) {
  uint4 r;
  r.x = (u32)f2bf(x.x) | ((u32)f2bf(x.y) << 16);
  r.y = (u32)f2bf(x.z) | ((u32)f2bf(x.w) << 16);
  r.z = (u32)f2bf(y.x) | ((u32)f2bf(y.y) << 16);
  r.w = (u32)f2bf(y.z) | ((u32)f2bf(y.w) << 16);
  return r;
}

// Swizzled LDS layout: element (col, e) of a [col][64e] bf16 tile at u16 offset
//   col*64 + (((e>>3) ^ col ^ (col>>3)) & 7)*8 + (e&7)
__device__ __forceinline__ int lds_addr(int col, int e) {
  return col * 64 + ((((e >> 3) ^ col ^ (col >> 3)) & 7) << 3) + (e & 7);
}

// transpose-pack: two e-rows (x = e, y = e+1), 8 cols each -> 8 ds_write_b32
__device__ __forceinline__ void pack_store(u16* __restrict__ lds, int colBase, int e,
                                           const uint4& x, const uint4& y) {
  const u32* xp = (const u32*)&x;
  const u32* yp = (const u32*)&y;
#pragma unroll
  for (int i = 0; i < 4; ++i) {
    u32 xv = xp[i], yv = yp[i];
    u32 lo = (xv & 0xffffu) | (yv << 16);
    u32 hi = (xv >> 16) | (yv & 0xffff0000u);
    int c0 = colBase + 2 * i;
    *(u32*)(lds + lds_addr(c0, e)) = lo;
    *(u32*)(lds + lds_addr(c0 + 1, e)) = hi;
  }
}

// ---------------- f32 -> bf16 cast (4 elems/thread) ----------------
__global__ void k_cast(const float* __restrict__ in, u16* __restrict__ out, int n4) {
  int i = blockIdx.x * 256 + threadIdx.x;
  if (i < n4) {
    float4 v = *(const float4*)(in + (size_t)i * 4);
    uint2 o;
    o.x = (u32)f2bf(v.x) | ((u32)f2bf(v.y) << 16);
    o.y = (u32)f2bf(v.z) | ((u32)f2bf(v.w) << 16);
    *(uint2*)(out + (size_t)i * 4) = o;
  }
}

// ---------------- CSR build ----------------
__global__ void k_hist(const int* __restrict__ rows, int* __restrict__ cnt) {
  int i = blockIdx.x * 256 + threadIdx.x;
  if (i < NEDGE) atomicAdd(&cnt[rows[i]], 1);
}

__global__ void k_bsum(const int* __restrict__ cnt, int* __restrict__ bsum) {
  __shared__ int sb[256];
  int t = threadIdx.x, i = blockIdx.x * 256 + t;
  sb[t] = (i < E_ENT) ? cnt[i] : 0;
  __syncthreads();
  for (int s = 128; s; s >>= 1) { if (t < s) sb[t] += sb[t + s]; __syncthreads(); }
  if (t == 0) bsum[blockIdx.x] = sb[0];
}

__global__ void k_scanb(const int* __restrict__ bsum, int* __restrict__ boff, int nb) {
  __shared__ int sb[256];
  int t = threadIdx.x;
  int v = (t < nb) ? bsum[t] : 0;
  sb[t] = v;
  __syncthreads();
  for (int o = 1; o < 256; o <<= 1) {
    int x = (t >= o) ? sb[t - o] : 0;
    __syncthreads();
    sb[t] += x;
    __syncthreads();
  }
  if (t < nb) boff[t] = sb[t] - v;
}

__global__ void k_apply(const int* __restrict__ cnt, const int* __restrict__ boff,
                        int* __restrict__ ptr, int* __restrict__ cur) {
  __shared__ int sb[256];
  int t = threadIdx.x, b = blockIdx.x, i = b * 256 + t;
  int v = (i < E_ENT) ? cnt[i] : 0;
  sb[t] = v;
  __syncthreads();
  for (int o = 1; o < 256; o <<= 1) {
    int x = (t >= o) ? sb[t - o] : 0;
    __syncthreads();
    sb[t] += x;
    __syncthreads();
  }
  if (i < E_ENT) { int ex = boff[b] + sb[t] - v; ptr[i] = ex; cur[i] = ex; }
  if (b == 0 && t == 0) ptr[E_ENT] = NEDGE;
}

__global__ void k_scat_e(const int* __restrict__ rows, const int* __restrict__ cols,
                         const int* __restrict__ rels, int* __restrict__ cur,
                         int* __restrict__ cs, int* __restrict__ rs) {
  int i = blockIdx.x * 256 + threadIdx.x;
  if (i < NEDGE) {
    int p = atomicAdd(&cur[rows[i]], 1);
    cs[p] = cols[i];
    rs[p] = rels[i];
  }
}

__global__ void k_scat_m(const int* __restrict__ rows, const int* __restrict__ cols,
                         const float* __restrict__ vals, int* __restrict__ cur,
                         int* __restrict__ cs, float* __restrict__ vs) {
  int i = blockIdx.x * 256 + threadIdx.x;
  if (i < NEDGE) {
    int p = atomicAdd(&cur[rows[i]], 1);
    cs[p] = cols[i];
    vs[p] = vals[i];
  }
}

// ---------------- fused [head|tail]^T @ X (M=2x500,K=50000,N=256), split-K, MFMA --------
// head/tail read DIRECTLY as f32 (no precast): A-staging loads masked float4,
// converts to bf16 at pack time. Round 1 also accumulates f32 column sums
// (nt==0 blocks only -> each W element counted exactly once), LDS-reduced to
// 64 atomics/block. XB: bf16 [E,256]. flat grid 1600, XCD-swizzled so each
// K-chunk's 32 tiles (16mt x 2nt) run on ONE XCD.
__device__ __forceinline__ void wtx_load(const float* __restrict__ WSel, const u16* __restrict__ XB,
                                         int eb, int e_end, int r0, int n0,
                                         int ap, int aq, int ep0, int ep1, int nq,
                                         float4& f00, float4& f01, float4& f10, float4& f11,
                                         uint4& b00, uint4& b01, uint4& b10, uint4& b11) {
  int ee = e_end - eb;
  int c0 = r0 + aq * 8;
  bool cv0 = c0 < R_REL, cv1 = (c0 + 4) < R_REL;  // R_REL multiple of 4 -> per-float4 mask exact
  bool r0ok = 2 * ap < ee, r1ok = 2 * ap + 1 < ee;
  const float* p = WSel + (size_t)(eb + 2 * ap) * R_REL + c0;
  f00 = ldf4(p, r0ok && cv0);
  f01 = ldf4(p + 4, r0ok && cv1);
  f10 = ldf4(p + R_REL, r1ok && cv0);
  f11 = ldf4(p + R_REL + 4, r1ok && cv1);
  const u16* q0 = XB + (size_t)(eb + 2 * ep0) * DD + n0 + nq * 8;
  b00 = ld4g(q0, 2 * ep0 < ee);
  b01 = ld4g(q0 + DD, 2 * ep0 + 1 < ee);
  const u16* q1 = XB + (size_t)(eb + 2 * ep1) * DD + n0 + nq * 8;
  b10 = ld4g(q1, 2 * ep1 < ee);
  b11 = ld4g(q1 + DD, 2 * ep1 + 1 < ee);
}

__global__ __launch_bounds__(256) void k_wtx(const float* __restrict__ HW,
                                             const float* __restrict__ TW,
                                             const u16* __restrict__ XB,
                                             float* __restrict__ P,
                                             float* __restrict__ sums) {
  __shared__ __align__(16) u16 lsa2[2 * 32 * 64];  // [H|T] A-tiles, swizzled
  __shared__ __align__(16) u16 lsb[128 * 64];      // B-tile, swizzled (reused as f32 scratch)
  const int tid = threadIdx.x;
  const int bid = blockIdx.x;
  const int swz = (bid & 7) * 200 + (bid >> 3);   // 1600 = 8*200, bijective XCD swizzle
  const int mtnt = swz & 31;
  const int mt = mtnt >> 1, nt = mtnt & 1;
  const int chunk = swz >> 5;
  const int r0 = mt * 32, n0 = nt * 128;
  const int lane = tid & 63, wv = tid >> 6;
  const int wm = (wv & 1) * 16, wn = (wv >> 1) * 64;
  const int l15 = lane & 15, lq = lane >> 4;
  const int ap = (tid & 127) >> 2, aq = tid & 3;  // A tile: e-pair, r-oct (per half)
  const int ep0 = tid >> 4, nq = tid & 15;        // B tiles: e-pairs ep0, ep0+16
  const int ep1 = ep0 + 16;
  const float* WSel = (tid < 128) ? HW : TW;
  u16* lsaSel = lsa2 + (tid >> 7) * (32 * 64);
  const bool dosum = (sums != nullptr) && (nt == 0);
  const int e_begin = chunk * KCHUNK;
  const int e_end = min(e_begin + KCHUNK, E_ENT);
  const int iters = (e_end - e_begin + 63) >> 6;

  f32x4 accH[4], accT[4];
#pragma unroll
  for (int t = 0; t < 4; ++t) { accH[t] = (f32x4)0.f; accT[t] = (f32x4)0.f; }
  float s0 = 0.f, s1 = 0.f, s2 = 0.f, s3 = 0.f, s4 = 0.f, s5 = 0.f, s6 = 0.f, s7 = 0.f;

  float4 f00, f01, f10, f11;
  uint4 b00, b01, b10, b11;
  wtx_load(WSel, XB, e_begin, e_end, r0, n0, ap, aq, ep0, ep1, nq,
           f00, f01, f10, f11, b00, b01, b10, b11);

  int eb = e_begin;
  for (int it = 0; it < iters; ++it) {
    __syncthreads();
    uint4 a0 = pk4(f00, f01), a1 = pk4(f10, f11);
    if (dosum) {
      s0 += f00.x + f10.x; s1 += f00.y + f10.y; s2 += f00.z + f10.z; s3 += f00.w + f10.w;
      s4 += f01.x + f11.x; s5 += f01.y + f11.y; s6 += f01.z + f11.z; s7 += f01.w + f11.w;
    }
    pack_store(lsaSel, aq * 8, 2 * ap, a0, a1);
    pack_store(lsb, nq * 8, 2 * ep0, b00, b01);
    pack_store(lsb, nq * 8, 2 * ep1, b10, b11);
    __syncthreads();
    eb += 64;
    if (it + 1 < iters)
      wtx_load(WSel, XB, eb, e_end, r0, n0, ap, aq, ep0, ep1, nq,
               f00, f01, f10, f11, b00, b01, b10, b11);
#pragma unroll
    for (int ks = 0; ks < 2; ++ks) {
      bf16x8 afH = *(const bf16x8*)(lsa2 + lds_addr(wm + l15, ks * 32 + lq * 8));
      bf16x8 afT = *(const bf16x8*)(lsa2 + 32 * 64 + lds_addr(wm + l15, ks * 32 + lq * 8));
#pragma unroll
      for (int t = 0; t < 4; ++t) {
        bf16x8 bv = *(const bf16x8*)(lsb + lds_addr(wn + t * 16 + l15, ks * 32 + lq * 8));
        accH[t] = __builtin_amdgcn_mfma_f32_16x16x32_bf16(afH, bv, accH[t], 0, 0, 0);
        accT[t] = __builtin_amdgcn_mfma_f32_16x16x32_bf16(afT, bv, accT[t], 0, 0, 0);
      }
    }
  }

  // column-sum LDS reduce (round 1, nt==0 only): scr[half][aq][j][ap]
  if (dosum) {
    __syncthreads();                 // last MFMA reads of lsb are done
    float* scr = (float*)lsb;        // need 2048 floats; lsb = 4096 floats
    int half = tid >> 7;
    int base = half * 1024 + aq * 256 + ap;
    scr[base + 0 * 32] = s0; scr[base + 1 * 32] = s1;
    scr[base + 2 * 32] = s2; scr[base + 3 * 32] = s3;
    scr[base + 4 * 32] = s4; scr[base + 5 * 32] = s5;
    scr[base + 6 * 32] = s6; scr[base + 7 * 32] = s7;
    __syncthreads();
    if (tid < 64) {
      int hh = tid >> 5, aq2 = (tid >> 3) & 3, j = tid & 7;
      float v = 0.f;
      for (int a = 0; a < 32; ++a) v += scr[hh * 1024 + aq2 * 256 + j * 32 + a];
      atomicAdd(&sums[hh * 512 + r0 + aq2 * 8 + j], v);
    }
  }

#pragma unroll
  for (int t = 0; t < 4; ++t) {
#pragma unroll
    for (int rg = 0; rg < 4; ++rg) {
      int row = r0 + wm + lq * 4 + rg;
      if (row < R_REL) {
        int col = n0 + wn + t * 16 + l15;
        atomicAdd(&P[row * D2 + col], accH[t][rg]);
        atomicAdd(&P[row * D2 + col + 256], accT[t][rg]);
      }
    }
  }
}

__global__ void k_fin(float* __restrict__ P, const float* __restrict__ hsum,
                      const float* __restrict__ tsum) {
  int i = blockIdx.x * 256 + threadIdx.x;
  if (i < R_REL * D2) {
    int r = i >> 9, c = i & 511;
    P[i] = P[i] / (c < 256 ? hsum[r] : tsum[r]);
  }
}

// ---------------- dense attention ----------------
__global__ __launch_bounds__(128) void k_infts(const float* __restrict__ feats,
                                               const float* __restrict__ w1,
                                               const float* __restrict__ w2, const float* __restrict__ b2,
                                               const float* __restrict__ w3, const float* __restrict__ b3,
                                               float* __restrict__ f1, float* __restrict__ f2) {
  __shared__ float fl[512];
  __shared__ float red[128];
  int r = blockIdx.x, t = threadIdx.x;
  for (int i = t; i < 512; i += 128) fl[i] = feats[r * 512 + i];
  __syncthreads();
  float a = 0.f;
  const float* wrow = w1 + (size_t)t * 512;
  for (int k = 0; k < 512; k += 4) {
    float4 v = *(const float4*)(wrow + k);
    a += fl[k + 0] * v.x + fl[k + 1] * v.y + fl[k + 2] * v.z + fl[k + 3] * v.w;
  }
  red[t] = a * w2[t];
  __syncthreads();
  for (int s = 64; s; s >>= 1) { if (t < s) red[t] += red[t + s]; __syncthreads(); }
  if (t == 0) f1[r] = red[0] + b2[0];
  __syncthreads();
  red[t] = a * w3[t];
  __syncthreads();
  for (int s = 64; s; s >>= 1) { if (t < s) red[t] += red[t + s]; __syncthreads(); }
  if (t == 0) f2[r] = red[0] + b3[0];
}

__global__ __launch_bounds__(256) void k_att(const float* __restrict__ adj,
                                             const float* __restrict__ f1,
                                             const float* __restrict__ f2,
                                             const float* __restrict__ vals,
                                             float* __restrict__ dH) {
  __shared__ float coef[512];
  __shared__ float red[256];
  int r = blockIdx.x, t = threadIdx.x;
  float f1r = f1[r];
  float z0, z1 = -1e30f;
  {
    float a = adj[r * 500 + t];
    float z = lrelu(a * (f1r + f2[t]));
    if (!(a > 0.f)) z += -1e9f;
    z0 = z;
  }
  int c1 = t + 256;
  if (c1 < 500) {
    float a = adj[r * 500 + c1];
    float z = lrelu(a * (f1r + f2[c1]));
    if (!(a > 0.f)) z += -1e9f;
    z1 = z;
  }
  red[t] = fmaxf(z0, z1);
  __syncthreads();
  for (int s = 128; s; s >>= 1) { if (t < s) red[t] = fmaxf(red[t], red[t + s]); __syncthreads(); }
  float m = red[0];
  __syncthreads();
  float e0 = expf(z0 - m);
  float e1 = (c1 < 500) ? expf(z1 - m) : 0.f;
  coef[t] = e0;
  coef[c1] = e1;
  red[t] = e0 + e1;
  __syncthreads();
  for (int s = 128; s; s >>= 1) { if (t < s) red[t] += red[t + s]; __syncthreads(); }
  float inv = 1.f / red[0];
  float accA = 0.f, accB = 0.f;
  int dA = t, dB = t + 256;
  for (int c = 0; c < 500; ++c) {
    float cf = coef[c];
    accA += cf * vals[c * 512 + dA];
    accB += cf * vals[c * 512 + dB];
  }
  dH[r * 512 + dA] = fmaxf(accA * inv, 0.f);
  dH[r * 512 + dB] = fmaxf(accB * inv, 0.f);
}

__global__ void k_score(const float* __restrict__ dH, const float* __restrict__ w,
                        const float* __restrict__ b, float* __restrict__ score) {
  int r = blockIdx.x, lane = threadIdx.x;  // block 64
  float a = 0.f;
  for (int k = lane; k < 512; k += 64) a += dH[r * 512 + k] * w[k];
  for (int o = 32; o; o >>= 1) a += __shfl_xor(a, o, 64);
  if (lane == 0) score[r] = a + b[0];
}

// EL[r] = exp(lrelu(score[r]) - gmax); same softmax result as per-row max-subtract
__global__ void k_els(const float* __restrict__ score, float* __restrict__ EL) {
  __shared__ float red[512];
  int t = threadIdx.x;  // block 512
  float v = (t < R_REL) ? lrelu(score[t]) : -3.0e38f;
  red[t] = v;
  __syncthreads();
  for (int s = 256; s; s >>= 1) { if (t < s) red[t] = fmaxf(red[t], red[t + s]); __syncthreads(); }
  float m = red[0];
  EL[t] = (t < R_REL) ? expf(v - m) : 0.f;
}

// ---------------- sparse attention (CSR, wave/row, shfl-broadcast gather) ----------------
__global__ __launch_bounds__(256) void k_spatt(const u16* __restrict__ src,
                                               const float* __restrict__ base,
                                               const int* __restrict__ ptr,
                                               const int* __restrict__ cols,
                                               const int* __restrict__ rels,
                                               const float* __restrict__ EL, float alpha,
                                               u16* __restrict__ outb, float* __restrict__ outf) {
  __shared__ float sEL[512];
  const int tid = threadIdx.x;
  sEL[tid] = EL[tid];
  sEL[tid + 256] = EL[tid + 256];
  __syncthreads();
  const int lane = tid & 63;
  const int e = blockIdx.x * 4 + (tid >> 6);
  int p0 = ptr[e], p1 = ptr[e + 1];
  float a0 = 0.f, a1 = 0.f, a2 = 0.f, a3 = 0.f;
  if (p1 > p0) {
    float s = 0.f;
    for (int j = p0 + lane; j < p1; j += 64) s += sEL[rels[j]];
    for (int o = 32; o; o >>= 1) s += __shfl_xor(s, o, 64);
    float inv = 1.f / s;
    for (int jb = p0; jb < p1; jb += 64) {
      int n = min(64, p1 - jb);
      int cl = 0; float wl = 0.f;
      if (lane < n) { cl = cols[jb + lane]; wl = sEL[rels[jb + lane]] * inv; }
      int jj = 0;
      for (; jj + 4 <= n; jj += 4) {
        int c0 = __shfl(cl, jj), c1 = __shfl(cl, jj + 1), c2 = __shfl(cl, jj + 2), c3 = __shfl(cl, jj + 3);
        float w0 = __shfl(wl, jj), w1 = __shfl(wl, jj + 1), w2 = __shfl(wl, jj + 2), w3 = __shfl(wl, jj + 3);
        uint2 v0 = *(const uint2*)(src + (size_t)c0 * DD + lane * 4);
        uint2 v1 = *(const uint2*)(src + (size_t)c1 * DD + lane * 4);
        uint2 v2 = *(const uint2*)(src + (size_t)c2 * DD + lane * 4);
        uint2 v3 = *(const uint2*)(src + (size_t)c3 * DD + lane * 4);
        a0 += w0 * bf2f((u16)(v0.x & 0xffffu)) + w1 * bf2f((u16)(v1.x & 0xffffu))
            + w2 * bf2f((u16)(v2.x & 0xffffu)) + w3 * bf2f((u16)(v3.x & 0xffffu));
        a1 += w0 * bf2f((u16)(v0.x >> 16)) + w1 * bf2f((u16)(v1.x >> 16))
            + w2 * bf2f((u16)(v2.x >> 16)) + w3 * bf2f((u16)(v3.x >> 16));
        a2 += w0 * bf2f((u16)(v0.y & 0xffffu)) + w1 * bf2f((u16)(v1.y & 0xffffu))
            + w2 * bf2f((u16)(v2.y & 0xffffu)) + w3 * bf2f((u16)(v3.y & 0xffffu));
        a3 += w0 * bf2f((u16)(v0.y >> 16)) + w1 * bf2f((u16)(v1.y >> 16))
            + w2 * bf2f((u16)(v2.y >> 16)) + w3 * bf2f((u16)(v3.y >> 16));
      }
      for (; jj < n; ++jj) {
        int c = __shfl(cl, jj);
        float w = __shfl(wl, jj);
        uint2 v = *(const uint2*)(src + (size_t)c * DD + lane * 4);
        a0 += w * bf2f((u16)(v.x & 0xffffu));
        a1 += w * bf2f((u16)(v.x >> 16));
        a2 += w * bf2f((u16)(v.y & 0xffffu));
        a3 += w * bf2f((u16)(v.y >> 16));
      }
    }
  }
  size_t off = (size_t)e * DD + lane * 4;
  float4 bv = *(const float4*)(base + off);
  float o0 = bv.x + alpha * fmaxf(a0, 0.f);
  float o1 = bv.y + alpha * fmaxf(a1, 0.f);
  float o2 = bv.z + alpha * fmaxf(a2, 0.f);
  float o3 = bv.w + alpha * fmaxf(a3, 0.f);
  uint2 ov;
  ov.x = (u32)f2bf(o0) | ((u32)f2bf(o1) << 16);
  ov.y = (u32)f2bf(o2) | ((u32)f2bf(o3) << 16);
  *(uint2*)(outb + off) = ov;
  if (outf) *(float4*)(outf + off) = make_float4(o0, o1, o2, o3);
}

// ---------------- GCN (CSR, wave/row, shfl-broadcast gather) ----------------
__global__ __launch_bounds__(256) void k_gcn(const u16* __restrict__ src,
                                             const int* __restrict__ ptr,
                                             const int* __restrict__ cols,
                                             const float* __restrict__ vals,
                                             const float* __restrict__ wg,
                                             float* __restrict__ gout) {
  const int lane = threadIdx.x & 63;
  const int e = blockIdx.x * 4 + (threadIdx.x >> 6);
  int p0 = ptr[e], p1 = ptr[e + 1];
  float a0 = 0.f, a1 = 0.f, a2 = 0.f, a3 = 0.f;
  for (int jb = p0; jb < p1; jb += 64) {
    int n = min(64, p1 - jb);
    int cl = 0; float wl = 0.f;
    if (lane < n) { cl = cols[jb + lane]; wl = vals[jb + lane]; }
    int jj = 0;
    for (; jj + 4 <= n; jj += 4) {
      int c0 = __shfl(cl, jj), c1 = __shfl(cl, jj + 1), c2 = __shfl(cl, jj + 2), c3 = __shfl(cl, jj + 3);
      float w0 = __shfl(wl, jj), w1 = __shfl(wl, jj + 1), w2 = __shfl(wl, jj + 2), w3 = __shfl(wl, jj + 3);
      uint2 v0 = *(const uint2*)(src + (size_t)c0 * DD + lane * 4);
      uint2 v1 = *(const uint2*)(src + (size_t)c1 * DD + lane * 4);
      uint2 v2 = *(const uint2*)(src + (size_t)c2 * DD + lane * 4);
      uint2 v3 = *(const uint2*)(src + (size_t)c3 * DD + lane * 4);
      a0 += w0 * bf2f((u16)(v0.x & 0xffffu)) + w1 * bf2f((u16)(v1.x & 0xffffu))
          + w2 * bf2f((u16)(v2.x & 0xffffu)) + w3 * bf2f((u16)(v3.x & 0xffffu));
      a1 += w0 * bf2f((u16)(v0.x >> 16)) + w1 * bf2f((u16)(v1.x >> 16))
          + w2 * bf2f((u16)(v2.x >> 16)) + w3 * bf2f((u16)(v3.x >> 16));
      a2 += w0 * bf2f((u16)(v0.y & 0xffffu)) + w1 * bf2f((u16)(v1.y & 0xffffu))
          + w2 * bf2f((u16)(v2.y & 0xffffu)) + w3 * bf2f((u16)(v3.y & 0xffffu));
      a3 += w0 * bf2f((u16)(v0.y >> 16)) + w1 * bf2f((u16)(v1.y >> 16))
          + w2 * bf2f((u16)(v2.y >> 16)) + w3 * bf2f((u16)(v3.y >> 16));
    }
    for (; jj < n; ++jj) {
      int c = __shfl(cl, jj);
      float w = __shfl(wl, jj);
      uint2 v = *(const uint2*)(src + (size_t)c * DD + lane * 4);
      a0 += w * bf2f((u16)(v.x & 0xffffu));
      a1 += w * bf2f((u16)(v.x >> 16));
      a2 += w * bf2f((u16)(v.y & 0xffffu));
      a3 += w * bf2f((u16)(v.y >> 16));
    }
  }
  int d = lane * 4;
  float4 wv = *(const float4*)(wg + d);
  float4 o = make_float4(fmaxf(a0 * wv.x, 0.f), fmaxf(a1 * wv.y, 0.f),
                         fmaxf(a2 * wv.z, 0.f), fmaxf(a3 * wv.w, 0.f));
  *(float4*)(gout + (size_t)e * DD + d) = o;
}

// ---------------- highway: h = sigmoid(x@K + bg) * g + (1-t) * x ----------------
// xb bf16; KB bf16 precast [256,256]; xf/g f32; in-place xf==outf safe.
// flat grid 3128, XCD-swizzled: 4 n-siblings of an e-tile stay on one XCD (xb reuse).
__global__ __launch_bounds__(256) void k_hw(const u16* __restrict__ xb,
                                            const float* __restrict__ xf,
                                            const float* __restrict__ g,
                                            const u16* __restrict__ KB,
                                            const float* __restrict__ bg,
                                            float* __restrict__ outf,
                                            u16* __restrict__ outb) {
  __shared__ __align__(16) u16 la[64 * 64];  // [m][k] swizzled
  __shared__ __align__(16) u16 lb[64 * 64];  // [n][k] swizzled
  const int tid = threadIdx.x;
  const int bid = blockIdx.x;
  const int swz = (bid & 7) * 391 + (bid >> 3);  // 3128 = 8 * 391, bijective
  const int e0 = (swz >> 2) * 64;
  const int n0 = (swz & 3) * 64;
  const int lane = tid & 63, wv = tid >> 6;
  const int m0 = wv * 16;
  const int l15 = lane & 15, lq = lane >> 4;
  const int am = tid >> 3, aoct = tid & 7;   // A tiles: rows am, am+32
  const int kp = tid >> 3, nq8 = tid & 7;    // B tile: k-pair 2kp, n-oct nq8
  f32x4 acc[4];
#pragma unroll
  for (int t = 0; t < 4; ++t) acc[t] = (f32x4)0.f;

  for (int kc = 0; kc < 4; ++kc) {
    {
      const u16* pa = xb + (size_t)(e0 + am) * DD + kc * 64 + aoct * 8;
      uint4 va = ld4g(pa, e0 + am < E_ENT);
      *(uint4*)(la + lds_addr(am, aoct * 8)) = va;
      const u16* pa2 = xb + (size_t)(e0 + am + 32) * DD + kc * 64 + aoct * 8;
      uint4 va2 = ld4g(pa2, e0 + am + 32 < E_ENT);
      *(uint4*)(la + lds_addr(am + 32, aoct * 8)) = va2;
      const u16* pb = KB + (size_t)(kc * 64 + 2 * kp) * DD + n0 + nq8 * 8;
      uint4 xk = *(const uint4*)pb;
      uint4 yk = *(const uint4*)(pb + DD);
      pack_store(lb, nq8 * 8, 2 * kp, xk, yk);
    }
    __syncthreads();
#pragma unroll
    for (int ks = 0; ks < 2; ++ks) {
      bf16x8 af = *(const bf16x8*)(la + lds_addr(m0 + l15, ks * 32 + lq * 8));
#pragma unroll
      for (int t = 0; t < 4; ++t) {
        bf16x8 bv = *(const bf16x8*)(lb + lds_addr(t * 16 + l15, ks * 32 + lq * 8));
        acc[t] = __builtin_amdgcn_mfma_f32_16x16x32_bf16(af, bv, acc[t], 0, 0, 0);
      }
    }
    __syncthreads();
  }
#pragma unroll
  for (int t = 0; t < 4; ++t) {
    int col = n0 + t * 16 + l15;
    float bgv = bg[col];
#pragma unroll
    for (int rg = 0; rg < 4; ++rg) {
      int row = e0 + m0 + lq * 4 + rg;
      if (row < E_ENT) {
        float z = acc[t][rg] + bgv;
        float tt = 1.f / (1.f + expf(-z));
        size_t off = (size_t)row * DD + col;
        float hv = tt * g[off] + (1.f - tt) * xf[off];
        outf[off] = hv;
        if (outb) outb[off] = f2bf(hv);
      }
    }
  }
}

// ---------------- host ----------------
extern "C" void kernel_launch(void* const* d_in, const int* in_sizes, int n_in,
                              void* d_out, int out_size, void* d_ws, size_t ws_size,
                              hipStream_t stream) {
  (void)in_sizes; (void)n_in; (void)out_size;
  const float* X0 = (const float*)d_in[0];
  const float* head = (const float*)d_in[1];
  const float* tail = (const float*)d_in[2];
  const float* adj = (const float*)d_in[3];
  const int* erow = (const int*)d_in[4];
  const int* ecol = (const int*)d_in[5];
  const int* erel = (const int*)d_in[6];
  const int* mrow = (const int*)d_in[7];
  const int* mcol = (const int*)d_in[8];
  const float* mval = (const float*)d_in[9];
  const float* w_self1 = (const float*)d_in[10];
  const float* w_self2 = (const float*)d_in[11];
  const float* b_self2 = (const float*)d_in[12];
  const float* w_self3 = (const float*)d_in[13];
  const float* b_self3 = (const float*)d_in[14];
  const float* w_sp1 = (const float*)d_in[15];
  const float* b_sp1 = (const float*)d_in[16];
  const float* w_dual1 = (const float*)d_in[17];
  const float* w_dual2 = (const float*)d_in[18];
  const float* b_dual2 = (const float*)d_in[19];
  const float* w_dual3 = (const float*)d_in[20];
  const float* b_dual3 = (const float*)d_in[21];
  const float* w_sp2 = (const float*)d_in[22];
  const float* b_sp2 = (const float*)d_in[23];
  const float* w_gcn1 = (const float*)d_in[24];
  const float* w_gcn2 = (const float*)d_in[25];
  const float* k_hw1 = (const float*)d_in[26];
  const float* bg_hw1 = (const float*)d_in[27];
  const float* k_hw2 = (const float*)d_in[28];
  const float* bg_hw2 = (const float*)d_in[29];

  char* ws = (char*)d_ws;
  size_t o = 0;
  auto take = [&](size_t bytes) -> char* {
    o = (o + 255) & ~(size_t)255;
    char* p = ws + o;
    o += bytes;
    return p;
  };
  u16* X0B  = (u16*)take((size_t)E_ENT * DD * 2);
  u16* PX1B = (u16*)take((size_t)E_ENT * DD * 2);
  u16* PX2B = (u16*)take((size_t)E_ENT * DD * 2);
  u16* H1B  = (u16*)take((size_t)E_ENT * DD * 2);
  float* PX2F = (float*)take((size_t)E_ENT * DD * 4);  // pX2, then h1
  float* G    = (float*)take((size_t)E_ENT * DD * 4);  // gcn out
  float* P1   = (float*)take((size_t)512 * 512 * 4);
  float* P2   = (float*)take((size_t)512 * 512 * 4);
  float* DH1  = (float*)take((size_t)512 * 512 * 4);
  float* DH2  = (float*)take((size_t)512 * 512 * 4);
  float* HS   = (float*)take(1024 * 4);
  float* F1   = (float*)take(512 * 4);
  float* F2   = (float*)take(512 * 4);
  float* SCORE = (float*)take(512 * 4);
  float* EL   = (float*)take(512 * 4);
  u16* KB1 = (u16*)take((size_t)DD * DD * 2);
  u16* KB2 = (u16*)take((size_t)DD * DD * 2);
  int* BSUM = (int*)take(256 * 4);
  int* BOFF = (int*)take(256 * 4);
  int* EPTR = (int*)take((size_t)(E_ENT + 1) * 4);
  int* ECUR = (int*)take((size_t)(E_ENT + 1) * 4);
  int* ECOLS = (int*)take((size_t)NEDGE * 4);
  int* ERELS = (int*)take((size_t)NEDGE * 4);
  int* MPTR = (int*)take((size_t)(E_ENT + 1) * 4);
  int* MCUR = (int*)take((size_t)(E_ENT + 1) * 4);
  int* MCOLS = (int*)take((size_t)NEDGE * 4);
  float* MVALS = (float*)take((size_t)NEDGE * 4);

  if (o > ws_size) {
    hipMemsetAsync(d_out, 0, (size_t)E_ENT * DD * 4, stream);
    return;
  }

  hipMemsetAsync(P1, 0, (size_t)512 * 512 * 4, stream);
  hipMemsetAsync(P2, 0, (size_t)512 * 512 * 4, stream);
  hipMemsetAsync(HS, 0, 1024 * 4, stream);
  hipMemsetAsync(ECUR, 0, (size_t)(E_ENT + 1) * 4, stream);
  hipMemsetAsync(MCUR, 0, (size_t)(E_ENT + 1) * 4, stream);

  const int GE = (NEDGE + 255) / 256;
  const int GB = (E_ENT + 255) / 256;

  k_cast<<<(E_ENT * DD / 4 + 255) / 256, 256, 0, stream>>>(X0, X0B, E_ENT * DD / 4);
  k_cast<<<64, 256, 0, stream>>>(k_hw1, KB1, DD * DD / 4);
  k_cast<<<64, 256, 0, stream>>>(k_hw2, KB2, DD * DD / 4);

  // CSR for edge_row
  k_hist<<<GE, 256, 0, stream>>>(erow, ECUR);
  k_bsum<<<GB, 256, 0, stream>>>(ECUR, BSUM);
  k_scanb<<<1, 256, 0, stream>>>(BSUM, BOFF, GB);
  k_apply<<<GB, 256, 0, stream>>>(ECUR, BOFF, EPTR, ECUR);
  k_scat_e<<<GE, 256, 0, stream>>>(erow, ecol, erel, ECUR, ECOLS, ERELS);
  // CSR for m_row
  k_hist<<<GE, 256, 0, stream>>>(mrow, MCUR);
  k_bsum<<<GB, 256, 0, stream>>>(MCUR, BSUM);
  k_scanb<<<1, 256, 0, stream>>>(BSUM, BOFF, GB);
  k_apply<<<GB, 256, 0, stream>>>(MCUR, BOFF, MPTR, MCUR);
  k_scat_m<<<GE, 256, 0, stream>>>(mrow, mcol, mval, MCUR, MCOLS, MVALS);

  // round 1: dX1 = compute_r(X0)  (f32 W direct; sums computed inline)
  k_wtx<<<32 * KSPLIT, 256, 0, stream>>>(head, tail, X0B, P1, HS);
  k_fin<<<1000, 256, 0, stream>>>(P1, HS, HS + 512);
  k_infts<<<500, 128, 0, stream>>>(P1, w_self1, w_self2, b_self2, w_self3, b_self3, F1, F2);
  k_att<<<500, 256, 0, stream>>>(adj, F1, F2, P1, DH1);
  k_score<<<500, 64, 0, stream>>>(DH1, w_sp1, b_sp1, SCORE);
  k_els<<<1, 512, 0, stream>>>(SCORE, EL);
  k_spatt<<<12500, 256, 0, stream>>>(X0B, X0, EPTR, ECOLS, ERELS, EL, 0.1f, PX1B, nullptr);

  // round 2: dX2 = compute_r(pX1)  (sums already in HS)
  k_wtx<<<32 * KSPLIT, 256, 0, stream>>>(head, tail, PX1B, P2, nullptr);
  k_fin<<<1000, 256, 0, stream>>>(P2, HS, HS + 512);
  k_infts<<<500, 128, 0, stream>>>(P2, w_dual1, w_dual2, b_dual2, w_dual3, b_dual3, F1, F2);
  k_att<<<500, 256, 0, stream>>>(adj, F1, F2, DH1, DH2);
  k_score<<<500, 64, 0, stream>>>(DH2, w_sp2, b_sp2, SCORE);
  k_els<<<1, 512, 0, stream>>>(SCORE, EL);
  k_spatt<<<12500, 256, 0, stream>>>(PX1B, X0, EPTR, ECOLS, ERELS, EL, 0.3f, PX2B, PX2F);

  // g1 = gcn(pX2); h1 = highway(pX2, g1)  (in place on PX2F)
  k_gcn<<<12500, 256, 0, stream>>>(PX2B, MPTR, MCOLS, MVALS, w_gcn1, G);
  k_hw<<<782 * 4, 256, 0, stream>>>(PX2B, PX2F, G, KB1, bg_hw1, PX2F, H1B);
  // g2 = gcn(h1); out = highway(h1, g2)
  k_gcn<<<12500, 256, 0, stream>>>(H1B, MPTR, MCOLS, MVALS, w_gcn2, G);
  k_hw<<<782 * 4, 256, 0, stream>>>(H1B, PX2F, G, KB2, bg_hw2, (float*)d_out, nullptr);
}